// Round 4
// baseline (253.618 us; speedup 1.0000x reference)
//
#include <hip/hip_runtime.h>
#include <hip/hip_bf16.h>

#define DIM 128
#define BM  64
#define NSH 4          // shadow counters per node (cuts atomic same-address chains 16 -> 4)

// ---------------------------------------------------------------------------
// K1: shadowed degree histogram.  c = e & 3.
//   degS_out laid out [NSH][N] (shadow-major, spreads channels)
//   degS_in  laid out [N][NSH] (node-major: this flattened array is the scan
//   input, so each node's NSH sub-buckets stay contiguous)
// ---------------------------------------------------------------------------
__global__ __launch_bounds__(256) void deg_kernel(const int* __restrict__ src,
                                                  const int* __restrict__ dst,
                                                  int* __restrict__ degS_out,
                                                  int* __restrict__ degS_in,
                                                  int n_edges, int n_nodes) {
    int e = blockIdx.x * 256 + threadIdx.x;
    if (e < n_edges) {
        int c = e & (NSH - 1);
        atomicAdd(&degS_out[c * n_nodes + src[e]], 1);
        atomicAdd(&degS_in[(size_t)dst[e] * NSH + c], 1);
    }
}

// ---------------------------------------------------------------------------
// K2: norm_src[i] = rsqrt(max(sum_c degS_out[c][i], 1))
// ---------------------------------------------------------------------------
__global__ __launch_bounds__(256) void norm_kernel(const int* __restrict__ degS_out,
                                                   float* __restrict__ norm_src,
                                                   int n_nodes) {
    int i = blockIdx.x * 256 + threadIdx.x;
    if (i < n_nodes) {
        int d = 0;
#pragma unroll
        for (int c = 0; c < NSH; ++c) d += degS_out[c * n_nodes + i];
        norm_src[i] = rsqrtf(fmaxf((float)d, 1.0f));
    }
}

// ---------------------------------------------------------------------------
// K3: exclusive scan of degS_in (n = NSH*N elems) -> offs[0..n].
// Redundant-prefix: block b re-sums deg[0..b*4096) then local scan; each
// thread handles 4 consecutive elements.  Single launch.
// ---------------------------------------------------------------------------
__global__ __launch_bounds__(1024) void scan4_kernel(const int* __restrict__ deg,
                                                     int* __restrict__ offs, int n) {
    __shared__ int w1[16], w2[16];
    const int tid = threadIdx.x, lane = tid & 63, wid = tid >> 6;
    const int base = blockIdx.x * 4096;

    // prefix = sum of all elements before this chunk (coalesced re-read)
    int part = 0;
    for (int i = base ? tid : n; i < base; i += 1024) part += deg[i];
#pragma unroll
    for (int o = 32; o; o >>= 1) part += __shfl_xor(part, o);
    if (lane == 0) w1[wid] = part;
    __syncthreads();
    int prefix = 0;
#pragma unroll
    for (int k = 0; k < 16; ++k) prefix += w1[k];

    // local: 4 elements per thread
    int i0 = base + tid * 4;
    int e0 = (i0 + 0 < n) ? deg[i0 + 0] : 0;
    int e1 = (i0 + 1 < n) ? deg[i0 + 1] : 0;
    int e2 = (i0 + 2 < n) ? deg[i0 + 2] : 0;
    int e3 = (i0 + 3 < n) ? deg[i0 + 3] : 0;
    int s  = e0 + e1 + e2 + e3;
    int sc = s;
#pragma unroll
    for (int o = 1; o < 64; o <<= 1) {
        int t = __shfl_up(sc, o);
        if (lane >= o) sc += t;
    }
    if (lane == 63) w2[wid] = sc;
    __syncthreads();
    int wpre = 0;
    for (int k = 0; k < wid; ++k) wpre += w2[k];
    int excl = prefix + wpre + sc - s;        // exclusive prefix of element i0
    int o1 = excl + e0, o2 = o1 + e1, o3 = o2 + e2, o4 = o3 + e3;
    if (i0 + 0 < n) offs[i0 + 1] = o1;
    if (i0 + 1 < n) offs[i0 + 2] = o2;
    if (i0 + 2 < n) offs[i0 + 3] = o3;
    if (i0 + 3 < n) offs[i0 + 4] = o4;
    if (base == 0 && tid == 0) offs[0] = 0;
}

// ---------------------------------------------------------------------------
// K4: bucket fill with shadowed cursors.  pos is unique within (dst, c)
// sub-bucket; node t's edges land in [offs[NSH*t], offs[NSH*t+NSH]).
// ---------------------------------------------------------------------------
__global__ __launch_bounds__(256) void fill_kernel(const int* __restrict__ src,
                                                   const int* __restrict__ dst,
                                                   const int* __restrict__ offs,
                                                   int* __restrict__ cursorS,
                                                   const float* __restrict__ norm_src,
                                                   int2* __restrict__ epk,
                                                   int n_edges) {
    int e = blockIdx.x * 256 + threadIdx.x;
    if (e >= n_edges) return;
    int c = e & (NSH - 1);
    int t = dst[e];
    int s = src[e];
    int slot = t * NSH + c;
    int pos = offs[slot] + atomicAdd(&cursorS[slot], 1);
    int2 p;
    p.x = s;
    p.y = __float_as_int(norm_src[s]);
    epk[pos] = p;
}

// ---------------------------------------------------------------------------
// K5: gather-SpMM.  One wave per dst node, float2 per lane, x4 unroll with
// independent accumulators.  deg_in derived from offs (free).
// ---------------------------------------------------------------------------
__global__ __launch_bounds__(256) void gather_kernel(const float* __restrict__ x,
                                                     const int2* __restrict__ epk,
                                                     const int* __restrict__ offs,
                                                     float* __restrict__ out,
                                                     int n_nodes) {
    int node = blockIdx.x * 4 + (threadIdx.x >> 6);
    if (node >= n_nodes) return;
    int lane = threadIdx.x & 63;
    int j   = offs[node * NSH];
    int end = offs[node * NSH + NSH];
    int deg = end - j;
    const float2* xp = reinterpret_cast<const float2*>(x);
    float ax0 = 0, ay0 = 0, ax1 = 0, ay1 = 0;
    float ax2 = 0, ay2 = 0, ax3 = 0, ay3 = 0;
    for (; j + 3 < end; j += 4) {
        int2 p0 = epk[j], p1 = epk[j + 1], p2 = epk[j + 2], p3 = epk[j + 3];
        float2 v0 = xp[(size_t)p0.x * 64 + lane];
        float2 v1 = xp[(size_t)p1.x * 64 + lane];
        float2 v2 = xp[(size_t)p2.x * 64 + lane];
        float2 v3 = xp[(size_t)p3.x * 64 + lane];
        float n0 = __int_as_float(p0.y), n1 = __int_as_float(p1.y);
        float n2 = __int_as_float(p2.y), n3 = __int_as_float(p3.y);
        ax0 = fmaf(v0.x, n0, ax0); ay0 = fmaf(v0.y, n0, ay0);
        ax1 = fmaf(v1.x, n1, ax1); ay1 = fmaf(v1.y, n1, ay1);
        ax2 = fmaf(v2.x, n2, ax2); ay2 = fmaf(v2.y, n2, ay2);
        ax3 = fmaf(v3.x, n3, ax3); ay3 = fmaf(v3.y, n3, ay3);
    }
    for (; j < end; ++j) {
        int2 p = epk[j];
        float2 v = xp[(size_t)p.x * 64 + lane];
        float ns = __int_as_float(p.y);
        ax0 = fmaf(v.x, ns, ax0); ay0 = fmaf(v.y, ns, ay0);
    }
    float nd = rsqrtf(fmaxf((float)deg, 1.0f));
    float2 r;
    r.x = (ax0 + ax1 + ax2 + ax3) * nd;
    r.y = (ay0 + ay1 + ay2 + ay3) * nd;
    reinterpret_cast<float2*>(out)[(size_t)node * 64 + lane] = r;
}

// ---------------------------------------------------------------------------
// K6: tiled fp32 GEMM + bias, in-place on out (unchanged from round 3).
// ---------------------------------------------------------------------------
__global__ __launch_bounds__(256) void gemm_kernel(float* __restrict__ out,
                                                   const float* __restrict__ Wg,
                                                   const float* __restrict__ bg,
                                                   int n_nodes) {
    __shared__ float As[DIM][BM + 1];
    __shared__ float Ws[DIM][DIM];
    const int tid = threadIdx.x;
    const int r0  = blockIdx.x * BM;

    {
        const float4* wsrc = reinterpret_cast<const float4*>(Wg);
        float4* wdst = reinterpret_cast<float4*>(&Ws[0][0]);
#pragma unroll
        for (int i = 0; i < 16; ++i) wdst[tid + i * 256] = wsrc[tid + i * 256];
    }
    {
#pragma unroll
        for (int i = 0; i < 8; ++i) {
            int linear = tid + i * 256;
            int r  = linear >> 5;
            int k4 = linear & 31;
            int row = r0 + r;
            float4 v = (row < n_nodes)
                         ? reinterpret_cast<const float4*>(out)[(size_t)row * 32 + k4]
                         : make_float4(0.f, 0.f, 0.f, 0.f);
            As[k4 * 4 + 0][r] = v.x;
            As[k4 * 4 + 1][r] = v.y;
            As[k4 * 4 + 2][r] = v.z;
            As[k4 * 4 + 3][r] = v.w;
        }
    }
    __syncthreads();

    const int cx = tid & 15;
    const int ry = tid >> 4;
    float acc[4][8];
#pragma unroll
    for (int rr = 0; rr < 4; ++rr)
#pragma unroll
        for (int cc = 0; cc < 8; ++cc) acc[rr][cc] = 0.f;

#pragma unroll 8
    for (int k = 0; k < DIM; ++k) {
        float4 a  = *reinterpret_cast<const float4*>(&As[k][ry * 4]);
        float4 b0 = *reinterpret_cast<const float4*>(&Ws[k][cx * 8]);
        float4 b1 = *reinterpret_cast<const float4*>(&Ws[k][cx * 8 + 4]);
        float av[4] = {a.x, a.y, a.z, a.w};
        float bv[8] = {b0.x, b0.y, b0.z, b0.w, b1.x, b1.y, b1.z, b1.w};
#pragma unroll
        for (int rr = 0; rr < 4; ++rr)
#pragma unroll
            for (int cc = 0; cc < 8; ++cc)
                acc[rr][cc] = fmaf(av[rr], bv[cc], acc[rr][cc]);
    }

    float bv[8];
#pragma unroll
    for (int cc = 0; cc < 8; ++cc) bv[cc] = bg[cx * 8 + cc];
#pragma unroll
    for (int rr = 0; rr < 4; ++rr) {
        int row = r0 + ry * 4 + rr;
        if (row >= n_nodes) continue;
        float4 o0, o1;
        o0.x = acc[rr][0] + bv[0]; o0.y = acc[rr][1] + bv[1];
        o0.z = acc[rr][2] + bv[2]; o0.w = acc[rr][3] + bv[3];
        o1.x = acc[rr][4] + bv[4]; o1.y = acc[rr][5] + bv[5];
        o1.z = acc[rr][6] + bv[6]; o1.w = acc[rr][7] + bv[7];
        float4* op = reinterpret_cast<float4*>(out + (size_t)row * DIM + cx * 8);
        op[0] = o0;
        op[1] = o1;
    }
}

extern "C" void kernel_launch(void* const* d_in, const int* in_sizes, int n_in,
                              void* d_out, int out_size, void* d_ws, size_t ws_size,
                              hipStream_t stream) {
    const float* x   = (const float*)d_in[0];
    const int*   src = (const int*)d_in[1];
    const int*   dst = (const int*)d_in[2];
    const float* W   = (const float*)d_in[3];
    const float* b   = (const float*)d_in[4];
    float* out = (float*)d_out;

    const int n_nodes = in_sizes[0] / DIM;
    const int n_edges = in_sizes[1];

    // ws layout (4B elems):
    // [degS_out NSH*N][degS_in NSH*N][cursorS NSH*N] (zeroed together)
    // [offs NSH*N+1][norm_src N][epk 2E]
    int*   degS_out = (int*)d_ws;
    int*   degS_in  = degS_out + NSH * n_nodes;
    int*   cursorS  = degS_in + NSH * n_nodes;
    int*   offs     = cursorS + NSH * n_nodes;
    float* norm_src = (float*)(offs + NSH * n_nodes + 1);
    int2*  epk      = (int2*)(norm_src + n_nodes);

    hipMemsetAsync(d_ws, 0, (size_t)3 * NSH * n_nodes * sizeof(int), stream);

    const int egrid = (n_edges + 255) / 256;
    const int ngrid = (n_nodes + 255) / 256;
    const int scan_n = NSH * n_nodes;

    deg_kernel<<<egrid, 256, 0, stream>>>(src, dst, degS_out, degS_in,
                                          n_edges, n_nodes);
    norm_kernel<<<ngrid, 256, 0, stream>>>(degS_out, norm_src, n_nodes);
    scan4_kernel<<<(scan_n + 4095) / 4096, 1024, 0, stream>>>(degS_in, offs, scan_n);
    fill_kernel<<<egrid, 256, 0, stream>>>(src, dst, offs, cursorS, norm_src,
                                           epk, n_edges);
    gather_kernel<<<(n_nodes + 3) / 4, 256, 0, stream>>>(x, epk, offs, out, n_nodes);
    gemm_kernel<<<(n_nodes + BM - 1) / BM, 256, 0, stream>>>(out, W, b, n_nodes);
}

// Round 5
// 204.227 us; speedup vs baseline: 1.2418x; 1.2418x over previous
//
#include <hip/hip_runtime.h>
#include <hip/hip_bf16.h>

#define DIM 128
#define BM  64

// ---------------------------------------------------------------------------
// K1: fused histogram + rank pass.  ONE atomic pass over edges:
//   rank[e] = atomicAdd(&cursor[dst[e]], 1)   (cursor ends up == deg_in)
//   atomicAdd(&deg_out[src[e]], 1)
// Device atomics cost ~40ns/op at a fixed per-op ceiling (round-4 evidence:
// WRITE_SIZE == n_atomics*32B, duration invariant to address spreading), so
// the win is cutting total atomic count 2.4M -> 1.6M.
// ---------------------------------------------------------------------------
__global__ __launch_bounds__(256) void passA_kernel(const int* __restrict__ src,
                                                    const int* __restrict__ dst,
                                                    int* __restrict__ deg_out,
                                                    int* __restrict__ cursor,
                                                    int* __restrict__ rank,
                                                    int n_edges) {
    int e = blockIdx.x * 256 + threadIdx.x;
    if (e < n_edges) {
        int t = dst[e];
        int s = src[e];
        rank[e] = atomicAdd(&cursor[t], 1);
        atomicAdd(&deg_out[s], 1);
    }
}

// ---------------------------------------------------------------------------
// K2: norm_src[i] = rsqrt(max(deg_out[i],1))
// ---------------------------------------------------------------------------
__global__ __launch_bounds__(256) void norm_kernel(const int* __restrict__ deg_out,
                                                   float* __restrict__ norm_src,
                                                   int n_nodes) {
    int i = blockIdx.x * 256 + threadIdx.x;
    if (i < n_nodes) norm_src[i] = rsqrtf(fmaxf((float)deg_out[i], 1.0f));
}

// ---------------------------------------------------------------------------
// K3: exclusive scan (redundant-prefix, 4 elems/thread, single launch).
// offs[0]=0, offs[i+1]=inclusive sum of deg[0..i].
// ---------------------------------------------------------------------------
__global__ __launch_bounds__(1024) void scan4_kernel(const int* __restrict__ deg,
                                                     int* __restrict__ offs, int n) {
    __shared__ int w1[16], w2[16];
    const int tid = threadIdx.x, lane = tid & 63, wid = tid >> 6;
    const int base = blockIdx.x * 4096;

    int part = 0;
    for (int i = base ? tid : n; i < base; i += 1024) part += deg[i];
#pragma unroll
    for (int o = 32; o; o >>= 1) part += __shfl_xor(part, o);
    if (lane == 0) w1[wid] = part;
    __syncthreads();
    int prefix = 0;
#pragma unroll
    for (int k = 0; k < 16; ++k) prefix += w1[k];

    int i0 = base + tid * 4;
    int e0 = (i0 + 0 < n) ? deg[i0 + 0] : 0;
    int e1 = (i0 + 1 < n) ? deg[i0 + 1] : 0;
    int e2 = (i0 + 2 < n) ? deg[i0 + 2] : 0;
    int e3 = (i0 + 3 < n) ? deg[i0 + 3] : 0;
    int s  = e0 + e1 + e2 + e3;
    int sc = s;
#pragma unroll
    for (int o = 1; o < 64; o <<= 1) {
        int t = __shfl_up(sc, o);
        if (lane >= o) sc += t;
    }
    if (lane == 63) w2[wid] = sc;
    __syncthreads();
    int wpre = 0;
    for (int k = 0; k < wid; ++k) wpre += w2[k];
    int excl = prefix + wpre + sc - s;
    int o1 = excl + e0, o2 = o1 + e1, o3 = o2 + e2, o4 = o3 + e3;
    if (i0 + 0 < n) offs[i0 + 1] = o1;
    if (i0 + 1 < n) offs[i0 + 2] = o2;
    if (i0 + 2 < n) offs[i0 + 3] = o3;
    if (i0 + 3 < n) offs[i0 + 4] = o4;
    if (base == 0 && tid == 0) offs[0] = 0;
}

// ---------------------------------------------------------------------------
// K4: x -> bf16 copy (round-to-nearest-even).  4 floats / thread.
// ---------------------------------------------------------------------------
__global__ __launch_bounds__(256) void cvt_kernel(const float* __restrict__ x,
                                                  ushort* __restrict__ xh, int n4) {
    int i = blockIdx.x * 256 + threadIdx.x;
    if (i >= n4) return;
    float4 v = reinterpret_cast<const float4*>(x)[i];
    ushort4 h;
    uint u;
    u = __float_as_uint(v.x); h.x = (ushort)((u + 0x7FFFu + ((u >> 16) & 1u)) >> 16);
    u = __float_as_uint(v.y); h.y = (ushort)((u + 0x7FFFu + ((u >> 16) & 1u)) >> 16);
    u = __float_as_uint(v.z); h.z = (ushort)((u + 0x7FFFu + ((u >> 16) & 1u)) >> 16);
    u = __float_as_uint(v.w); h.w = (ushort)((u + 0x7FFFu + ((u >> 16) & 1u)) >> 16);
    reinterpret_cast<ushort4*>(xh)[i] = h;
}

// ---------------------------------------------------------------------------
// K5: bucket fill, NO atomics.  pos = offs[dst] + rank.
// ---------------------------------------------------------------------------
__global__ __launch_bounds__(256) void fill_kernel(const int* __restrict__ src,
                                                   const int* __restrict__ dst,
                                                   const int* __restrict__ offs,
                                                   const int* __restrict__ rank,
                                                   int* __restrict__ esrc,
                                                   int n_edges) {
    int e = blockIdx.x * 256 + threadIdx.x;
    if (e >= n_edges) return;
    esrc[offs[dst[e]] + rank[e]] = src[e];
}

// ---------------------------------------------------------------------------
// K6a: gather-SpMM, bf16 rows.  One wave per dst node; lane holds 2 dims
// (one uint = 2 bf16).  norm_src[s] is a wave-uniform broadcast load.
// x4 unroll, independent accumulators.
// ---------------------------------------------------------------------------
__global__ __launch_bounds__(256) void gather_bf16_kernel(const ushort* __restrict__ xh,
                                                          const int* __restrict__ esrc,
                                                          const float* __restrict__ norm_src,
                                                          const int* __restrict__ offs,
                                                          float* __restrict__ out,
                                                          int n_nodes) {
    int node = blockIdx.x * 4 + (threadIdx.x >> 6);
    if (node >= n_nodes) return;
    int lane = threadIdx.x & 63;
    int j = offs[node], end = offs[node + 1];
    int deg = end - j;
    const uint* xp = reinterpret_cast<const uint*>(xh);
    float a0x = 0, a0y = 0, a1x = 0, a1y = 0;
    float a2x = 0, a2y = 0, a3x = 0, a3y = 0;
    for (; j + 3 < end; j += 4) {
        int s0 = esrc[j], s1 = esrc[j + 1], s2 = esrc[j + 2], s3 = esrc[j + 3];
        uint u0 = xp[(size_t)s0 * 64 + lane];
        uint u1 = xp[(size_t)s1 * 64 + lane];
        uint u2 = xp[(size_t)s2 * 64 + lane];
        uint u3 = xp[(size_t)s3 * 64 + lane];
        float n0 = norm_src[s0], n1 = norm_src[s1];
        float n2 = norm_src[s2], n3 = norm_src[s3];
        a0x = fmaf(__uint_as_float(u0 << 16), n0, a0x);
        a0y = fmaf(__uint_as_float(u0 & 0xFFFF0000u), n0, a0y);
        a1x = fmaf(__uint_as_float(u1 << 16), n1, a1x);
        a1y = fmaf(__uint_as_float(u1 & 0xFFFF0000u), n1, a1y);
        a2x = fmaf(__uint_as_float(u2 << 16), n2, a2x);
        a2y = fmaf(__uint_as_float(u2 & 0xFFFF0000u), n2, a2y);
        a3x = fmaf(__uint_as_float(u3 << 16), n3, a3x);
        a3y = fmaf(__uint_as_float(u3 & 0xFFFF0000u), n3, a3y);
    }
    for (; j < end; ++j) {
        int s = esrc[j];
        uint u = xp[(size_t)s * 64 + lane];
        float ns = norm_src[s];
        a0x = fmaf(__uint_as_float(u << 16), ns, a0x);
        a0y = fmaf(__uint_as_float(u & 0xFFFF0000u), ns, a0y);
    }
    float nd = rsqrtf(fmaxf((float)deg, 1.0f));
    float2 r;
    r.x = (a0x + a1x + a2x + a3x) * nd;
    r.y = (a0y + a1y + a2y + a3y) * nd;
    reinterpret_cast<float2*>(out)[(size_t)node * 64 + lane] = r;
}

// ---------------------------------------------------------------------------
// K6b: fp32 fallback gather (used only if ws too small for xh).
// ---------------------------------------------------------------------------
__global__ __launch_bounds__(256) void gather_f32_kernel(const float* __restrict__ x,
                                                         const int* __restrict__ esrc,
                                                         const float* __restrict__ norm_src,
                                                         const int* __restrict__ offs,
                                                         float* __restrict__ out,
                                                         int n_nodes) {
    int node = blockIdx.x * 4 + (threadIdx.x >> 6);
    if (node >= n_nodes) return;
    int lane = threadIdx.x & 63;
    int j = offs[node], end = offs[node + 1];
    int deg = end - j;
    const float2* xp = reinterpret_cast<const float2*>(x);
    float a0x = 0, a0y = 0, a1x = 0, a1y = 0;
    float a2x = 0, a2y = 0, a3x = 0, a3y = 0;
    for (; j + 3 < end; j += 4) {
        int s0 = esrc[j], s1 = esrc[j + 1], s2 = esrc[j + 2], s3 = esrc[j + 3];
        float2 v0 = xp[(size_t)s0 * 64 + lane];
        float2 v1 = xp[(size_t)s1 * 64 + lane];
        float2 v2 = xp[(size_t)s2 * 64 + lane];
        float2 v3 = xp[(size_t)s3 * 64 + lane];
        float n0 = norm_src[s0], n1 = norm_src[s1];
        float n2 = norm_src[s2], n3 = norm_src[s3];
        a0x = fmaf(v0.x, n0, a0x); a0y = fmaf(v0.y, n0, a0y);
        a1x = fmaf(v1.x, n1, a1x); a1y = fmaf(v1.y, n1, a1y);
        a2x = fmaf(v2.x, n2, a2x); a2y = fmaf(v2.y, n2, a2y);
        a3x = fmaf(v3.x, n3, a3x); a3y = fmaf(v3.y, n3, a3y);
    }
    for (; j < end; ++j) {
        int s = esrc[j];
        float2 v = xp[(size_t)s * 64 + lane];
        float ns = norm_src[s];
        a0x = fmaf(v.x, ns, a0x); a0y = fmaf(v.y, ns, a0y);
    }
    float nd = rsqrtf(fmaxf((float)deg, 1.0f));
    float2 r;
    r.x = (a0x + a1x + a2x + a3x) * nd;
    r.y = (a0y + a1y + a2y + a3y) * nd;
    reinterpret_cast<float2*>(out)[(size_t)node * 64 + lane] = r;
}

// ---------------------------------------------------------------------------
// K7: tiled fp32 GEMM + bias, in-place on out (unchanged; verified r3/r4).
// ---------------------------------------------------------------------------
__global__ __launch_bounds__(256) void gemm_kernel(float* __restrict__ out,
                                                   const float* __restrict__ Wg,
                                                   const float* __restrict__ bg,
                                                   int n_nodes) {
    __shared__ float As[DIM][BM + 1];
    __shared__ float Ws[DIM][DIM];
    const int tid = threadIdx.x;
    const int r0  = blockIdx.x * BM;

    {
        const float4* wsrc = reinterpret_cast<const float4*>(Wg);
        float4* wdst = reinterpret_cast<float4*>(&Ws[0][0]);
#pragma unroll
        for (int i = 0; i < 16; ++i) wdst[tid + i * 256] = wsrc[tid + i * 256];
    }
    {
#pragma unroll
        for (int i = 0; i < 8; ++i) {
            int linear = tid + i * 256;
            int r  = linear >> 5;
            int k4 = linear & 31;
            int row = r0 + r;
            float4 v = (row < n_nodes)
                         ? reinterpret_cast<const float4*>(out)[(size_t)row * 32 + k4]
                         : make_float4(0.f, 0.f, 0.f, 0.f);
            As[k4 * 4 + 0][r] = v.x;
            As[k4 * 4 + 1][r] = v.y;
            As[k4 * 4 + 2][r] = v.z;
            As[k4 * 4 + 3][r] = v.w;
        }
    }
    __syncthreads();

    const int cx = tid & 15;
    const int ry = tid >> 4;
    float acc[4][8];
#pragma unroll
    for (int rr = 0; rr < 4; ++rr)
#pragma unroll
        for (int cc = 0; cc < 8; ++cc) acc[rr][cc] = 0.f;

#pragma unroll 8
    for (int k = 0; k < DIM; ++k) {
        float4 a  = *reinterpret_cast<const float4*>(&As[k][ry * 4]);
        float4 b0 = *reinterpret_cast<const float4*>(&Ws[k][cx * 8]);
        float4 b1 = *reinterpret_cast<const float4*>(&Ws[k][cx * 8 + 4]);
        float av[4] = {a.x, a.y, a.z, a.w};
        float bv[8] = {b0.x, b0.y, b0.z, b0.w, b1.x, b1.y, b1.z, b1.w};
#pragma unroll
        for (int rr = 0; rr < 4; ++rr)
#pragma unroll
            for (int cc = 0; cc < 8; ++cc)
                acc[rr][cc] = fmaf(av[rr], bv[cc], acc[rr][cc]);
    }

    float bv[8];
#pragma unroll
    for (int cc = 0; cc < 8; ++cc) bv[cc] = bg[cx * 8 + cc];
#pragma unroll
    for (int rr = 0; rr < 4; ++rr) {
        int row = r0 + ry * 4 + rr;
        if (row >= n_nodes) continue;
        float4 o0, o1;
        o0.x = acc[rr][0] + bv[0]; o0.y = acc[rr][1] + bv[1];
        o0.z = acc[rr][2] + bv[2]; o0.w = acc[rr][3] + bv[3];
        o1.x = acc[rr][4] + bv[4]; o1.y = acc[rr][5] + bv[5];
        o1.z = acc[rr][6] + bv[6]; o1.w = acc[rr][7] + bv[7];
        float4* op = reinterpret_cast<float4*>(out + (size_t)row * DIM + cx * 8);
        op[0] = o0;
        op[1] = o1;
    }
}

extern "C" void kernel_launch(void* const* d_in, const int* in_sizes, int n_in,
                              void* d_out, int out_size, void* d_ws, size_t ws_size,
                              hipStream_t stream) {
    const float* x   = (const float*)d_in[0];
    const int*   src = (const int*)d_in[1];
    const int*   dst = (const int*)d_in[2];
    const float* W   = (const float*)d_in[3];
    const float* b   = (const float*)d_in[4];
    float* out = (float*)d_out;

    const int n_nodes = in_sizes[0] / DIM;
    const int n_edges = in_sizes[1];

    // ws layout (4B units):
    // [deg_out N][cursor N] (zeroed) [offs N+1][norm_src N][rank E][esrc E][xh N*DIM bf16]
    int*   deg_out  = (int*)d_ws;
    int*   cursor   = deg_out + n_nodes;
    int*   offs     = cursor + n_nodes;
    float* norm_src = (float*)(offs + n_nodes + 1);
    int*   rank     = (int*)(norm_src + n_nodes);
    int*   esrc     = rank + n_edges;
    ushort* xh      = (ushort*)(esrc + n_edges);

    const size_t need_base = ((size_t)4 * n_nodes + 1 + 2 * (size_t)n_edges) * 4;
    const size_t need_xh   = need_base + (size_t)n_nodes * DIM * 2;
    const bool use_bf16 = (ws_size >= need_xh);

    hipMemsetAsync(d_ws, 0, (size_t)2 * n_nodes * sizeof(int), stream);

    const int egrid = (n_edges + 255) / 256;
    const int ngrid = (n_nodes + 255) / 256;

    passA_kernel<<<egrid, 256, 0, stream>>>(src, dst, deg_out, cursor, rank, n_edges);
    norm_kernel<<<ngrid, 256, 0, stream>>>(deg_out, norm_src, n_nodes);
    scan4_kernel<<<(n_nodes + 4095) / 4096, 1024, 0, stream>>>(cursor, offs, n_nodes);
    if (use_bf16) {
        int n4 = n_nodes * DIM / 4;
        cvt_kernel<<<(n4 + 255) / 256, 256, 0, stream>>>(x, xh, n4);
    }
    fill_kernel<<<egrid, 256, 0, stream>>>(src, dst, offs, rank, esrc, n_edges);
    if (use_bf16) {
        gather_bf16_kernel<<<(n_nodes + 3) / 4, 256, 0, stream>>>(xh, esrc, norm_src,
                                                                  offs, out, n_nodes);
    } else {
        gather_f32_kernel<<<(n_nodes + 3) / 4, 256, 0, stream>>>(x, esrc, norm_src,
                                                                 offs, out, n_nodes);
    }
    gemm_kernel<<<(n_nodes + BM - 1) / BM, 256, 0, stream>>>(out, W, b, n_nodes);
}

// Round 6
// 197.765 us; speedup vs baseline: 1.2824x; 1.0327x over previous
//
#include <hip/hip_runtime.h>
#include <hip/hip_bf16.h>

#define DIM 128
#define BM  64
#define HALF_NODES 25088            // nodes per LDS-resident half
#define HALF_PAIRS (HALF_NODES / 2) // 12544 uints = 50176 B LDS

// ---------------------------------------------------------------------------
// K1: chunked histograms, LDS-only atomics.  Block c processes edge chunk c.
// Two u16 counters packed per uint (chunk <= 65535 edges guaranteed by host).
// Dumps per-chunk histograms of dst (histD) and src (histS).
// ---------------------------------------------------------------------------
__global__ __launch_bounds__(1024) void hist_kernel(const int* __restrict__ src,
                                                    const int* __restrict__ dst,
                                                    uint* __restrict__ histD,
                                                    uint* __restrict__ histS,
                                                    int n_edges, int pairs_row,
                                                    int nhalves, int chunk) {
    __shared__ uint h[HALF_PAIRS];
    const int c   = blockIdx.x;
    const int tid = threadIdx.x;
    const int beg = c * chunk;
    const int end = min(beg + chunk, n_edges);
    for (int pass = 0; pass < 2; ++pass) {
        const int* key = pass ? src : dst;
        uint* outb     = pass ? histS : histD;
        for (int half = 0; half < nhalves; ++half) {
            for (int j = tid; j < HALF_PAIRS; j += 1024) h[j] = 0;
            __syncthreads();
            const int lo = half * HALF_NODES;
            for (int e = beg + tid; e < end; e += 1024) {
                int r = key[e] - lo;
                if ((unsigned)r < HALF_NODES)
                    atomicAdd(&h[r >> 1], 1u << ((r & 1) * 16));
            }
            __syncthreads();
            uint* row = outb + (size_t)c * pairs_row + half * HALF_PAIRS;
            for (int j = tid; j < HALF_PAIRS; j += 1024) row[j] = h[j];
            __syncthreads();
        }
    }
}

// ---------------------------------------------------------------------------
// K2: per-node exclusive prefix over chunks, IN PLACE (hist -> chunk prefix),
// emitting deg_in (from histD) and norm_src (from histS).  Thread owns one
// packed column (2 nodes); reads are coalesced across threads per chunk.
// ---------------------------------------------------------------------------
__global__ __launch_bounds__(256) void prefix_kernel(uint* __restrict__ histD,
                                                     uint* __restrict__ histS,
                                                     int* __restrict__ deg_in,
                                                     float* __restrict__ norm_src,
                                                     int pairs_row, int n_nodes,
                                                     int nchunk) {
    int id = blockIdx.x * 256 + threadIdx.x;
    bool isS = id >= pairs_row;
    int j = isS ? id - pairs_row : id;
    if (j >= pairs_row) return;
    uint* col = (isS ? histS : histD) + j;
    uint run0 = 0, run1 = 0;
    for (int c = 0; c < nchunk; ++c) {
        uint v = col[(size_t)c * pairs_row];
        col[(size_t)c * pairs_row] = run0 | (run1 << 16);
        run0 += v & 0xFFFFu;
        run1 += v >> 16;
    }
    int n0 = 2 * j, n1 = 2 * j + 1;
    if (isS) {
        if (n0 < n_nodes) norm_src[n0] = rsqrtf(fmaxf((float)run0, 1.0f));
        if (n1 < n_nodes) norm_src[n1] = rsqrtf(fmaxf((float)run1, 1.0f));
    } else {
        deg_in[n0] = (int)run0;   // padded nodes get 0 (no edges)
        deg_in[n1] = (int)run1;
    }
}

// ---------------------------------------------------------------------------
// K3: exclusive scan (redundant-prefix, 4 elems/thread, single launch).
// ---------------------------------------------------------------------------
__global__ __launch_bounds__(1024) void scan4_kernel(const int* __restrict__ deg,
                                                     int* __restrict__ offs, int n) {
    __shared__ int w1[16], w2[16];
    const int tid = threadIdx.x, lane = tid & 63, wid = tid >> 6;
    const int base = blockIdx.x * 4096;

    int part = 0;
    for (int i = base ? tid : n; i < base; i += 1024) part += deg[i];
#pragma unroll
    for (int o = 32; o; o >>= 1) part += __shfl_xor(part, o);
    if (lane == 0) w1[wid] = part;
    __syncthreads();
    int prefix = 0;
#pragma unroll
    for (int k = 0; k < 16; ++k) prefix += w1[k];

    int i0 = base + tid * 4;
    int e0 = (i0 + 0 < n) ? deg[i0 + 0] : 0;
    int e1 = (i0 + 1 < n) ? deg[i0 + 1] : 0;
    int e2 = (i0 + 2 < n) ? deg[i0 + 2] : 0;
    int e3 = (i0 + 3 < n) ? deg[i0 + 3] : 0;
    int s  = e0 + e1 + e2 + e3;
    int sc = s;
#pragma unroll
    for (int o = 1; o < 64; o <<= 1) {
        int t = __shfl_up(sc, o);
        if (lane >= o) sc += t;
    }
    if (lane == 63) w2[wid] = sc;
    __syncthreads();
    int wpre = 0;
    for (int k = 0; k < wid; ++k) wpre += w2[k];
    int excl = prefix + wpre + sc - s;
    int o1 = excl + e0, o2 = o1 + e1, o3 = o2 + e2, o4 = o3 + e3;
    if (i0 + 0 < n) offs[i0 + 1] = o1;
    if (i0 + 1 < n) offs[i0 + 2] = o2;
    if (i0 + 2 < n) offs[i0 + 3] = o3;
    if (i0 + 3 < n) offs[i0 + 4] = o4;
    if (base == 0 && tid == 0) offs[0] = 0;
}

// ---------------------------------------------------------------------------
// K4: x -> bf16 copy (round-to-nearest-even).
// ---------------------------------------------------------------------------
__global__ __launch_bounds__(256) void cvt_kernel(const float* __restrict__ x,
                                                  ushort* __restrict__ xh, int n4) {
    int i = blockIdx.x * 256 + threadIdx.x;
    if (i >= n4) return;
    float4 v = reinterpret_cast<const float4*>(x)[i];
    ushort4 h;
    uint u;
    u = __float_as_uint(v.x); h.x = (ushort)((u + 0x7FFFu + ((u >> 16) & 1u)) >> 16);
    u = __float_as_uint(v.y); h.y = (ushort)((u + 0x7FFFu + ((u >> 16) & 1u)) >> 16);
    u = __float_as_uint(v.z); h.z = (ushort)((u + 0x7FFFu + ((u >> 16) & 1u)) >> 16);
    u = __float_as_uint(v.w); h.w = (ushort)((u + 0x7FFFu + ((u >> 16) & 1u)) >> 16);
    reinterpret_cast<ushort4*>(xh)[i] = h;
}

// ---------------------------------------------------------------------------
// K5: counting-sort scatter, LDS-rank + chunk-prefix.  NO global atomics.
// pos = offs[dst] + histD_prefix[c][dst] + lds_rank  (bijective onto [0,E)).
// Bucket-internal order is arbitrary (sum is order-insensitive).
// ---------------------------------------------------------------------------
__global__ __launch_bounds__(1024) void fill_kernel(const int* __restrict__ src,
                                                    const int* __restrict__ dst,
                                                    const int* __restrict__ offs,
                                                    const uint* __restrict__ histD,
                                                    int* __restrict__ esrc,
                                                    int n_edges, int pairs_row,
                                                    int nhalves, int chunk) {
    __shared__ uint h[HALF_PAIRS];
    const int c   = blockIdx.x;
    const int tid = threadIdx.x;
    const int beg = c * chunk;
    const int end = min(beg + chunk, n_edges);
    const uint* prow = histD + (size_t)c * pairs_row;
    for (int half = 0; half < nhalves; ++half) {
        for (int j = tid; j < HALF_PAIRS; j += 1024) h[j] = 0;
        __syncthreads();
        const int lo = half * HALF_NODES;
        for (int e = beg + tid; e < end; e += 1024) {
            int t = dst[e];
            int r = t - lo;
            if ((unsigned)r < HALF_NODES) {
                uint old = atomicAdd(&h[r >> 1], 1u << ((r & 1) * 16));
                int lr   = (r & 1) ? (int)(old >> 16) : (int)(old & 0xFFFFu);
                uint pf  = prow[t >> 1];
                int pref = (t & 1) ? (int)(pf >> 16) : (int)(pf & 0xFFFFu);
                esrc[offs[t] + pref + lr] = src[e];
            }
        }
        __syncthreads();
    }
}

// ---------------------------------------------------------------------------
// K6a: gather-SpMM, bf16 rows (unchanged from round 5).
// ---------------------------------------------------------------------------
__global__ __launch_bounds__(256) void gather_bf16_kernel(const ushort* __restrict__ xh,
                                                          const int* __restrict__ esrc,
                                                          const float* __restrict__ norm_src,
                                                          const int* __restrict__ offs,
                                                          float* __restrict__ out,
                                                          int n_nodes) {
    int node = blockIdx.x * 4 + (threadIdx.x >> 6);
    if (node >= n_nodes) return;
    int lane = threadIdx.x & 63;
    int j = offs[node], end = offs[node + 1];
    int deg = end - j;
    const uint* xp = reinterpret_cast<const uint*>(xh);
    float a0x = 0, a0y = 0, a1x = 0, a1y = 0;
    float a2x = 0, a2y = 0, a3x = 0, a3y = 0;
    for (; j + 3 < end; j += 4) {
        int s0 = esrc[j], s1 = esrc[j + 1], s2 = esrc[j + 2], s3 = esrc[j + 3];
        uint u0 = xp[(size_t)s0 * 64 + lane];
        uint u1 = xp[(size_t)s1 * 64 + lane];
        uint u2 = xp[(size_t)s2 * 64 + lane];
        uint u3 = xp[(size_t)s3 * 64 + lane];
        float n0 = norm_src[s0], n1 = norm_src[s1];
        float n2 = norm_src[s2], n3 = norm_src[s3];
        a0x = fmaf(__uint_as_float(u0 << 16), n0, a0x);
        a0y = fmaf(__uint_as_float(u0 & 0xFFFF0000u), n0, a0y);
        a1x = fmaf(__uint_as_float(u1 << 16), n1, a1x);
        a1y = fmaf(__uint_as_float(u1 & 0xFFFF0000u), n1, a1y);
        a2x = fmaf(__uint_as_float(u2 << 16), n2, a2x);
        a2y = fmaf(__uint_as_float(u2 & 0xFFFF0000u), n2, a2y);
        a3x = fmaf(__uint_as_float(u3 << 16), n3, a3x);
        a3y = fmaf(__uint_as_float(u3 & 0xFFFF0000u), n3, a3y);
    }
    for (; j < end; ++j) {
        int s = esrc[j];
        uint u = xp[(size_t)s * 64 + lane];
        float ns = norm_src[s];
        a0x = fmaf(__uint_as_float(u << 16), ns, a0x);
        a0y = fmaf(__uint_as_float(u & 0xFFFF0000u), ns, a0y);
    }
    float nd = rsqrtf(fmaxf((float)deg, 1.0f));
    float2 r;
    r.x = (a0x + a1x + a2x + a3x) * nd;
    r.y = (a0y + a1y + a2y + a3y) * nd;
    reinterpret_cast<float2*>(out)[(size_t)node * 64 + lane] = r;
}

// ---------------------------------------------------------------------------
// K6b: fp32 fallback gather.
// ---------------------------------------------------------------------------
__global__ __launch_bounds__(256) void gather_f32_kernel(const float* __restrict__ x,
                                                         const int* __restrict__ esrc,
                                                         const float* __restrict__ norm_src,
                                                         const int* __restrict__ offs,
                                                         float* __restrict__ out,
                                                         int n_nodes) {
    int node = blockIdx.x * 4 + (threadIdx.x >> 6);
    if (node >= n_nodes) return;
    int lane = threadIdx.x & 63;
    int j = offs[node], end = offs[node + 1];
    int deg = end - j;
    const float2* xp = reinterpret_cast<const float2*>(x);
    float a0x = 0, a0y = 0, a1x = 0, a1y = 0;
    float a2x = 0, a2y = 0, a3x = 0, a3y = 0;
    for (; j + 3 < end; j += 4) {
        int s0 = esrc[j], s1 = esrc[j + 1], s2 = esrc[j + 2], s3 = esrc[j + 3];
        float2 v0 = xp[(size_t)s0 * 64 + lane];
        float2 v1 = xp[(size_t)s1 * 64 + lane];
        float2 v2 = xp[(size_t)s2 * 64 + lane];
        float2 v3 = xp[(size_t)s3 * 64 + lane];
        float n0 = norm_src[s0], n1 = norm_src[s1];
        float n2 = norm_src[s2], n3 = norm_src[s3];
        a0x = fmaf(v0.x, n0, a0x); a0y = fmaf(v0.y, n0, a0y);
        a1x = fmaf(v1.x, n1, a1x); a1y = fmaf(v1.y, n1, a1y);
        a2x = fmaf(v2.x, n2, a2x); a2y = fmaf(v2.y, n2, a2y);
        a3x = fmaf(v3.x, n3, a3x); a3y = fmaf(v3.y, n3, a3y);
    }
    for (; j < end; ++j) {
        int s = esrc[j];
        float2 v = xp[(size_t)s * 64 + lane];
        float ns = norm_src[s];
        a0x = fmaf(v.x, ns, a0x); a0y = fmaf(v.y, ns, a0y);
    }
    float nd = rsqrtf(fmaxf((float)deg, 1.0f));
    float2 r;
    r.x = (a0x + a1x + a2x + a3x) * nd;
    r.y = (a0y + a1y + a2y + a3y) * nd;
    reinterpret_cast<float2*>(out)[(size_t)node * 64 + lane] = r;
}

// ---------------------------------------------------------------------------
// K7: tiled fp32 GEMM + bias, in-place on out (unchanged; verified r3-r5).
// ---------------------------------------------------------------------------
__global__ __launch_bounds__(256) void gemm_kernel(float* __restrict__ out,
                                                   const float* __restrict__ Wg,
                                                   const float* __restrict__ bg,
                                                   int n_nodes) {
    __shared__ float As[DIM][BM + 1];
    __shared__ float Ws[DIM][DIM];
    const int tid = threadIdx.x;
    const int r0  = blockIdx.x * BM;

    {
        const float4* wsrc = reinterpret_cast<const float4*>(Wg);
        float4* wdst = reinterpret_cast<float4*>(&Ws[0][0]);
#pragma unroll
        for (int i = 0; i < 16; ++i) wdst[tid + i * 256] = wsrc[tid + i * 256];
    }
    {
#pragma unroll
        for (int i = 0; i < 8; ++i) {
            int linear = tid + i * 256;
            int r  = linear >> 5;
            int k4 = linear & 31;
            int row = r0 + r;
            float4 v = (row < n_nodes)
                         ? reinterpret_cast<const float4*>(out)[(size_t)row * 32 + k4]
                         : make_float4(0.f, 0.f, 0.f, 0.f);
            As[k4 * 4 + 0][r] = v.x;
            As[k4 * 4 + 1][r] = v.y;
            As[k4 * 4 + 2][r] = v.z;
            As[k4 * 4 + 3][r] = v.w;
        }
    }
    __syncthreads();

    const int cx = tid & 15;
    const int ry = tid >> 4;
    float acc[4][8];
#pragma unroll
    for (int rr = 0; rr < 4; ++rr)
#pragma unroll
        for (int cc = 0; cc < 8; ++cc) acc[rr][cc] = 0.f;

#pragma unroll 8
    for (int k = 0; k < DIM; ++k) {
        float4 a  = *reinterpret_cast<const float4*>(&As[k][ry * 4]);
        float4 b0 = *reinterpret_cast<const float4*>(&Ws[k][cx * 8]);
        float4 b1 = *reinterpret_cast<const float4*>(&Ws[k][cx * 8 + 4]);
        float av[4] = {a.x, a.y, a.z, a.w};
        float bv[8] = {b0.x, b0.y, b0.z, b0.w, b1.x, b1.y, b1.z, b1.w};
#pragma unroll
        for (int rr = 0; rr < 4; ++rr)
#pragma unroll
            for (int cc = 0; cc < 8; ++cc)
                acc[rr][cc] = fmaf(av[rr], bv[cc], acc[rr][cc]);
    }

    float bv[8];
#pragma unroll
    for (int cc = 0; cc < 8; ++cc) bv[cc] = bg[cx * 8 + cc];
#pragma unroll
    for (int rr = 0; rr < 4; ++rr) {
        int row = r0 + ry * 4 + rr;
        if (row >= n_nodes) continue;
        float4 o0, o1;
        o0.x = acc[rr][0] + bv[0]; o0.y = acc[rr][1] + bv[1];
        o0.z = acc[rr][2] + bv[2]; o0.w = acc[rr][3] + bv[3];
        o1.x = acc[rr][4] + bv[4]; o1.y = acc[rr][5] + bv[5];
        o1.z = acc[rr][6] + bv[6]; o1.w = acc[rr][7] + bv[7];
        float4* op = reinterpret_cast<float4*>(out + (size_t)row * DIM + cx * 8);
        op[0] = o0;
        op[1] = o1;
    }
}

extern "C" void kernel_launch(void* const* d_in, const int* in_sizes, int n_in,
                              void* d_out, int out_size, void* d_ws, size_t ws_size,
                              hipStream_t stream) {
    const float* x   = (const float*)d_in[0];
    const int*   src = (const int*)d_in[1];
    const int*   dst = (const int*)d_in[2];
    const float* W   = (const float*)d_in[3];
    const float* b   = (const float*)d_in[4];
    float* out = (float*)d_out;

    const int n_nodes = in_sizes[0] / DIM;
    const int n_edges = in_sizes[1];

    const int nhalves   = (n_nodes + HALF_NODES - 1) / HALF_NODES;
    const int npad      = nhalves * HALF_NODES;
    const int pairs_row = npad / 2;

    // Pick chunk count C and bf16 usage to fit ws.  Chunk edges must stay
    // < 65536 for the packed-u16 counters (C >= 16 suffices for E = 800K).
    auto need = [&](int C, bool bf) -> size_t {
        return 4ull * ((size_t)2 * npad + 1 + n_nodes +
                       2ull * C * pairs_row + n_edges) +
               (bf ? 2ull * n_nodes * DIM : 0);
    };
    int C = 64;
    bool use_bf16 = true;
    if (ws_size < need(64, true)) {
        use_bf16 = false;
        if (ws_size < need(64, false)) C = 32;
        if (ws_size < need(32, false)) C = 16;
    }
    const int chunk = (n_edges + C - 1) / C;

    // ws layout (4B units), all fully overwritten -> NO memset needed:
    // [deg_in npad][offs npad+1][norm_src N][histD C*pairs][histS C*pairs]
    // [esrc E][xh N*DIM bf16 (optional)]
    int*    deg_in   = (int*)d_ws;
    int*    offs     = deg_in + npad;
    float*  norm_src = (float*)(offs + npad + 1);
    uint*   histD    = (uint*)(norm_src + n_nodes);
    uint*   histS    = histD + (size_t)C * pairs_row;
    int*    esrc     = (int*)(histS + (size_t)C * pairs_row);
    ushort* xh       = (ushort*)(esrc + n_edges);

    hist_kernel<<<C, 1024, 0, stream>>>(src, dst, histD, histS,
                                        n_edges, pairs_row, nhalves, chunk);
    prefix_kernel<<<(2 * pairs_row + 255) / 256, 256, 0, stream>>>(
        histD, histS, deg_in, norm_src, pairs_row, n_nodes, C);
    scan4_kernel<<<(npad + 4095) / 4096, 1024, 0, stream>>>(deg_in, offs, npad);
    if (use_bf16) {
        int n4 = n_nodes * DIM / 4;
        cvt_kernel<<<(n4 + 255) / 256, 256, 0, stream>>>(x, xh, n4);
    }
    fill_kernel<<<C, 1024, 0, stream>>>(src, dst, offs, histD, esrc,
                                        n_edges, pairs_row, nhalves, chunk);
    if (use_bf16) {
        gather_bf16_kernel<<<(n_nodes + 3) / 4, 256, 0, stream>>>(
            xh, esrc, norm_src, offs, out, n_nodes);
    } else {
        gather_f32_kernel<<<(n_nodes + 3) / 4, 256, 0, stream>>>(
            x, esrc, norm_src, offs, out, n_nodes);
    }
    gemm_kernel<<<(n_nodes + BM - 1) / BM, 256, 0, stream>>>(out, W, b, n_nodes);
}

// Round 7
// 164.026 us; speedup vs baseline: 1.5462x; 1.2057x over previous
//
#include <hip/hip_runtime.h>
#include <hip/hip_bf16.h>

#define DIM 128
#define BM  64
#define HALF_NODES 25088            // nodes per LDS half
#define HALF_PAIRS (HALF_NODES / 2) // 12544 uints
#define FULL_PAIRS (2 * HALF_PAIRS) // 25088 uints = 100 KB LDS window

// ---------------------------------------------------------------------------
// K1: chunked histograms, LDS-only atomics, 2-half window resident (100 KB).
// Block c processes edge chunk c; one edge-read per pass.  On the dst pass
// the LDS atomicAdd's returned old value IS the within-chunk rank -> rank[e].
// ---------------------------------------------------------------------------
__global__ __launch_bounds__(1024) void hist_kernel(const int* __restrict__ src,
                                                    const int* __restrict__ dst,
                                                    uint* __restrict__ histD,
                                                    uint* __restrict__ histS,
                                                    int* __restrict__ rank,
                                                    int n_edges, int pairs_row,
                                                    int nhalves, int chunk) {
    __shared__ uint h[FULL_PAIRS];
    const int c   = blockIdx.x;
    const int tid = threadIdx.x;
    const int beg = c * chunk;
    const int end = min(beg + chunk, n_edges);
    for (int pass = 0; pass < 2; ++pass) {
        const int* key = pass ? src : dst;
        uint* outb     = pass ? histS : histD;
        for (int hbase = 0; hbase < nhalves; hbase += 2) {
            const int plo    = hbase * HALF_PAIRS;
            const int wpairs = min(FULL_PAIRS, pairs_row - plo);
            const int wnodes = wpairs * 2;
            const int lo     = plo * 2;
            for (int j = tid; j < wpairs; j += 1024) h[j] = 0;
            __syncthreads();
            for (int e = beg + tid; e < end; e += 1024) {
                int r = key[e] - lo;
                if ((unsigned)r < (unsigned)wnodes) {
                    uint old = atomicAdd(&h[r >> 1], 1u << ((r & 1) * 16));
                    if (pass == 0)
                        rank[e] = (r & 1) ? (int)(old >> 16) : (int)(old & 0xFFFFu);
                }
            }
            __syncthreads();
            uint* row = outb + (size_t)c * pairs_row + plo;
            for (int j = tid; j < wpairs; j += 1024) row[j] = h[j];
            __syncthreads();
        }
    }
}

// ---------------------------------------------------------------------------
// K2: per-node exclusive prefix over chunks, in place, emitting deg_in and
// norm_src as byproducts.
// ---------------------------------------------------------------------------
__global__ __launch_bounds__(256) void prefix_kernel(uint* __restrict__ histD,
                                                     uint* __restrict__ histS,
                                                     int* __restrict__ deg_in,
                                                     float* __restrict__ norm_src,
                                                     int pairs_row, int n_nodes,
                                                     int nchunk) {
    int id = blockIdx.x * 256 + threadIdx.x;
    bool isS = id >= pairs_row;
    int j = isS ? id - pairs_row : id;
    if (j >= pairs_row) return;
    uint* col = (isS ? histS : histD) + j;
    uint run0 = 0, run1 = 0;
    for (int c = 0; c < nchunk; ++c) {
        uint v = col[(size_t)c * pairs_row];
        col[(size_t)c * pairs_row] = run0 | (run1 << 16);
        run0 += v & 0xFFFFu;
        run1 += v >> 16;
    }
    int n0 = 2 * j, n1 = 2 * j + 1;
    if (isS) {
        if (n0 < n_nodes) norm_src[n0] = rsqrtf(fmaxf((float)run0, 1.0f));
        if (n1 < n_nodes) norm_src[n1] = rsqrtf(fmaxf((float)run1, 1.0f));
    } else {
        deg_in[n0] = (int)run0;
        deg_in[n1] = (int)run1;
    }
}

// ---------------------------------------------------------------------------
// K3: exclusive scan (redundant-prefix, 4 elems/thread, single launch).
// ---------------------------------------------------------------------------
__global__ __launch_bounds__(1024) void scan4_kernel(const int* __restrict__ deg,
                                                     int* __restrict__ offs, int n) {
    __shared__ int w1[16], w2[16];
    const int tid = threadIdx.x, lane = tid & 63, wid = tid >> 6;
    const int base = blockIdx.x * 4096;

    int part = 0;
    for (int i = base ? tid : n; i < base; i += 1024) part += deg[i];
#pragma unroll
    for (int o = 32; o; o >>= 1) part += __shfl_xor(part, o);
    if (lane == 0) w1[wid] = part;
    __syncthreads();
    int prefix = 0;
#pragma unroll
    for (int k = 0; k < 16; ++k) prefix += w1[k];

    int i0 = base + tid * 4;
    int e0 = (i0 + 0 < n) ? deg[i0 + 0] : 0;
    int e1 = (i0 + 1 < n) ? deg[i0 + 1] : 0;
    int e2 = (i0 + 2 < n) ? deg[i0 + 2] : 0;
    int e3 = (i0 + 3 < n) ? deg[i0 + 3] : 0;
    int s  = e0 + e1 + e2 + e3;
    int sc = s;
#pragma unroll
    for (int o = 1; o < 64; o <<= 1) {
        int t = __shfl_up(sc, o);
        if (lane >= o) sc += t;
    }
    if (lane == 63) w2[wid] = sc;
    __syncthreads();
    int wpre = 0;
    for (int k = 0; k < wid; ++k) wpre += w2[k];
    int excl = prefix + wpre + sc - s;
    int o1 = excl + e0, o2 = o1 + e1, o3 = o2 + e2, o4 = o3 + e3;
    if (i0 + 0 < n) offs[i0 + 1] = o1;
    if (i0 + 1 < n) offs[i0 + 2] = o2;
    if (i0 + 2 < n) offs[i0 + 3] = o3;
    if (i0 + 3 < n) offs[i0 + 4] = o4;
    if (base == 0 && tid == 0) offs[0] = 0;
}

// ---------------------------------------------------------------------------
// K4: x -> bf16 copy (round-to-nearest-even).
// ---------------------------------------------------------------------------
__global__ __launch_bounds__(256) void cvt_kernel(const float* __restrict__ x,
                                                  ushort* __restrict__ xh, int n4) {
    int i = blockIdx.x * 256 + threadIdx.x;
    if (i >= n4) return;
    float4 v = reinterpret_cast<const float4*>(x)[i];
    ushort4 h;
    uint u;
    u = __float_as_uint(v.x); h.x = (ushort)((u + 0x7FFFu + ((u >> 16) & 1u)) >> 16);
    u = __float_as_uint(v.y); h.y = (ushort)((u + 0x7FFFu + ((u >> 16) & 1u)) >> 16);
    u = __float_as_uint(v.z); h.z = (ushort)((u + 0x7FFFu + ((u >> 16) & 1u)) >> 16);
    u = __float_as_uint(v.w); h.w = (ushort)((u + 0x7FFFu + ((u >> 16) & 1u)) >> 16);
    reinterpret_cast<ushort4*>(xh)[i] = h;
}

// ---------------------------------------------------------------------------
// K5: streaming scatter, no LDS, no atomics.
// pos = offs[dst] + chunk_prefix[c][dst] + rank[e]   (bijective onto [0,E)).
// ---------------------------------------------------------------------------
__global__ __launch_bounds__(256) void fill_kernel(const int* __restrict__ src,
                                                   const int* __restrict__ dst,
                                                   const int* __restrict__ offs,
                                                   const uint* __restrict__ histD,
                                                   const int* __restrict__ rank,
                                                   int* __restrict__ esrc,
                                                   int n_edges, int pairs_row,
                                                   int chunk) {
    int e = blockIdx.x * 256 + threadIdx.x;
    if (e >= n_edges) return;
    int t = dst[e];
    int c = e / chunk;
    uint pf = histD[(size_t)c * pairs_row + (t >> 1)];
    int pref = (t & 1) ? (int)(pf >> 16) : (int)(pf & 0xFFFFu);
    esrc[offs[t] + pref + rank[e]] = src[e];
}

// ---------------------------------------------------------------------------
// K6a: gather-SpMM, bf16 rows (unchanged).
// ---------------------------------------------------------------------------
__global__ __launch_bounds__(256) void gather_bf16_kernel(const ushort* __restrict__ xh,
                                                          const int* __restrict__ esrc,
                                                          const float* __restrict__ norm_src,
                                                          const int* __restrict__ offs,
                                                          float* __restrict__ out,
                                                          int n_nodes) {
    int node = blockIdx.x * 4 + (threadIdx.x >> 6);
    if (node >= n_nodes) return;
    int lane = threadIdx.x & 63;
    int j = offs[node], end = offs[node + 1];
    int deg = end - j;
    const uint* xp = reinterpret_cast<const uint*>(xh);
    float a0x = 0, a0y = 0, a1x = 0, a1y = 0;
    float a2x = 0, a2y = 0, a3x = 0, a3y = 0;
    for (; j + 3 < end; j += 4) {
        int s0 = esrc[j], s1 = esrc[j + 1], s2 = esrc[j + 2], s3 = esrc[j + 3];
        uint u0 = xp[(size_t)s0 * 64 + lane];
        uint u1 = xp[(size_t)s1 * 64 + lane];
        uint u2 = xp[(size_t)s2 * 64 + lane];
        uint u3 = xp[(size_t)s3 * 64 + lane];
        float n0 = norm_src[s0], n1 = norm_src[s1];
        float n2 = norm_src[s2], n3 = norm_src[s3];
        a0x = fmaf(__uint_as_float(u0 << 16), n0, a0x);
        a0y = fmaf(__uint_as_float(u0 & 0xFFFF0000u), n0, a0y);
        a1x = fmaf(__uint_as_float(u1 << 16), n1, a1x);
        a1y = fmaf(__uint_as_float(u1 & 0xFFFF0000u), n1, a1y);
        a2x = fmaf(__uint_as_float(u2 << 16), n2, a2x);
        a2y = fmaf(__uint_as_float(u2 & 0xFFFF0000u), n2, a2y);
        a3x = fmaf(__uint_as_float(u3 << 16), n3, a3x);
        a3y = fmaf(__uint_as_float(u3 & 0xFFFF0000u), n3, a3y);
    }
    for (; j < end; ++j) {
        int s = esrc[j];
        uint u = xp[(size_t)s * 64 + lane];
        float ns = norm_src[s];
        a0x = fmaf(__uint_as_float(u << 16), ns, a0x);
        a0y = fmaf(__uint_as_float(u & 0xFFFF0000u), ns, a0y);
    }
    float nd = rsqrtf(fmaxf((float)deg, 1.0f));
    float2 r;
    r.x = (a0x + a1x + a2x + a3x) * nd;
    r.y = (a0y + a1y + a2y + a3y) * nd;
    reinterpret_cast<float2*>(out)[(size_t)node * 64 + lane] = r;
}

// ---------------------------------------------------------------------------
// K6b: fp32 fallback gather.
// ---------------------------------------------------------------------------
__global__ __launch_bounds__(256) void gather_f32_kernel(const float* __restrict__ x,
                                                         const int* __restrict__ esrc,
                                                         const float* __restrict__ norm_src,
                                                         const int* __restrict__ offs,
                                                         float* __restrict__ out,
                                                         int n_nodes) {
    int node = blockIdx.x * 4 + (threadIdx.x >> 6);
    if (node >= n_nodes) return;
    int lane = threadIdx.x & 63;
    int j = offs[node], end = offs[node + 1];
    int deg = end - j;
    const float2* xp = reinterpret_cast<const float2*>(x);
    float a0x = 0, a0y = 0, a1x = 0, a1y = 0;
    float a2x = 0, a2y = 0, a3x = 0, a3y = 0;
    for (; j + 3 < end; j += 4) {
        int s0 = esrc[j], s1 = esrc[j + 1], s2 = esrc[j + 2], s3 = esrc[j + 3];
        float2 v0 = xp[(size_t)s0 * 64 + lane];
        float2 v1 = xp[(size_t)s1 * 64 + lane];
        float2 v2 = xp[(size_t)s2 * 64 + lane];
        float2 v3 = xp[(size_t)s3 * 64 + lane];
        float n0 = norm_src[s0], n1 = norm_src[s1];
        float n2 = norm_src[s2], n3 = norm_src[s3];
        a0x = fmaf(v0.x, n0, a0x); a0y = fmaf(v0.y, n0, a0y);
        a1x = fmaf(v1.x, n1, a1x); a1y = fmaf(v1.y, n1, a1y);
        a2x = fmaf(v2.x, n2, a2x); a2y = fmaf(v2.y, n2, a2y);
        a3x = fmaf(v3.x, n3, a3x); a3y = fmaf(v3.y, n3, a3y);
    }
    for (; j < end; ++j) {
        int s = esrc[j];
        float2 v = xp[(size_t)s * 64 + lane];
        float ns = norm_src[s];
        a0x = fmaf(v.x, ns, a0x); a0y = fmaf(v.y, ns, a0y);
    }
    float nd = rsqrtf(fmaxf((float)deg, 1.0f));
    float2 r;
    r.x = (a0x + a1x + a2x + a3x) * nd;
    r.y = (a0y + a1y + a2y + a3y) * nd;
    reinterpret_cast<float2*>(out)[(size_t)node * 64 + lane] = r;
}

// ---------------------------------------------------------------------------
// K7: tiled fp32 GEMM + bias, in-place, CONFLICT-FREE LDS layout.
//  - As row-major [BM][DIM+4]: staging = contiguous b128 (free);
//    compute reads are 4 scalar b32 broadcasts (free).
//  - Ws [DIM][DIM]: compute reads two float4 at cx*4 and 64+cx*4
//    (16 addrs x 4 banks = all 32 banks 2-way = free).
// Thread (cx,ry): rows ry*4..+3, cols {cx*4..+3} u {64+cx*4..+3}.
// ---------------------------------------------------------------------------
__global__ __launch_bounds__(256) void gemm_kernel(float* __restrict__ out,
                                                   const float* __restrict__ Wg,
                                                   const float* __restrict__ bg,
                                                   int n_nodes) {
    __shared__ float As[BM][DIM + 4];   // 64 x 132 f32 = 33.8 KB
    __shared__ float Ws[DIM][DIM];      // 64 KB
    const int tid = threadIdx.x;
    const int r0  = blockIdx.x * BM;

    // stage W: contiguous float4 copy (conflict-free)
    {
        const float4* wsrc = reinterpret_cast<const float4*>(Wg);
        float4* wdst = reinterpret_cast<float4*>(&Ws[0][0]);
#pragma unroll
        for (int i = 0; i < 16; ++i) wdst[tid + i * 256] = wsrc[tid + i * 256];
    }
    // stage A row-major: global-coalesced b128 read, contiguous b128 LDS write
    {
#pragma unroll
        for (int i = 0; i < 8; ++i) {
            int linear = tid + i * 256;       // 0..2047
            int r  = linear >> 5;             // row within tile
            int k4 = linear & 31;             // float4 index along k
            int row = r0 + r;
            float4 v = (row < n_nodes)
                         ? reinterpret_cast<const float4*>(out)[(size_t)row * 32 + k4]
                         : make_float4(0.f, 0.f, 0.f, 0.f);
            *reinterpret_cast<float4*>(&As[r][k4 * 4]) = v;
        }
    }
    __syncthreads();

    const int cx = tid & 15;   // col groups: cx*4..+3 and 64+cx*4..+3
    const int ry = tid >> 4;   // rows ry*4..+3
    float acc[4][8];
#pragma unroll
    for (int rr = 0; rr < 4; ++rr)
#pragma unroll
        for (int cc = 0; cc < 8; ++cc) acc[rr][cc] = 0.f;

#pragma unroll 4
    for (int k = 0; k < DIM; ++k) {
        float a0 = As[ry * 4 + 0][k];
        float a1 = As[ry * 4 + 1][k];
        float a2 = As[ry * 4 + 2][k];
        float a3 = As[ry * 4 + 3][k];
        float4 b0 = *reinterpret_cast<const float4*>(&Ws[k][cx * 4]);
        float4 b1 = *reinterpret_cast<const float4*>(&Ws[k][64 + cx * 4]);
        float av[4] = {a0, a1, a2, a3};
        float bv[8] = {b0.x, b0.y, b0.z, b0.w, b1.x, b1.y, b1.z, b1.w};
#pragma unroll
        for (int rr = 0; rr < 4; ++rr)
#pragma unroll
            for (int cc = 0; cc < 8; ++cc)
                acc[rr][cc] = fmaf(av[rr], bv[cc], acc[rr][cc]);
    }

    float bv0[4], bv1[4];
#pragma unroll
    for (int cc = 0; cc < 4; ++cc) {
        bv0[cc] = bg[cx * 4 + cc];
        bv1[cc] = bg[64 + cx * 4 + cc];
    }
#pragma unroll
    for (int rr = 0; rr < 4; ++rr) {
        int row = r0 + ry * 4 + rr;
        if (row >= n_nodes) continue;
        float4 o0, o1;
        o0.x = acc[rr][0] + bv0[0]; o0.y = acc[rr][1] + bv0[1];
        o0.z = acc[rr][2] + bv0[2]; o0.w = acc[rr][3] + bv0[3];
        o1.x = acc[rr][4] + bv1[0]; o1.y = acc[rr][5] + bv1[1];
        o1.z = acc[rr][6] + bv1[2]; o1.w = acc[rr][7] + bv1[3];
        float* op = out + (size_t)row * DIM;
        *reinterpret_cast<float4*>(op + cx * 4)      = o0;
        *reinterpret_cast<float4*>(op + 64 + cx * 4) = o1;
    }
}

extern "C" void kernel_launch(void* const* d_in, const int* in_sizes, int n_in,
                              void* d_out, int out_size, void* d_ws, size_t ws_size,
                              hipStream_t stream) {
    const float* x   = (const float*)d_in[0];
    const int*   src = (const int*)d_in[1];
    const int*   dst = (const int*)d_in[2];
    const float* W   = (const float*)d_in[3];
    const float* b   = (const float*)d_in[4];
    float* out = (float*)d_out;

    const int n_nodes = in_sizes[0] / DIM;
    const int n_edges = in_sizes[1];

    const int nhalves   = (n_nodes + HALF_NODES - 1) / HALF_NODES;
    const int npad      = nhalves * HALF_NODES;
    const int pairs_row = npad / 2;

    // Fit check: prefer bf16 (big gather win), then chunk count C.
    auto need = [&](int C, bool bf) -> size_t {
        return 4ull * ((size_t)2 * npad + 1 + n_nodes +
                       2ull * C * pairs_row + 2ull * n_edges) +
               (bf ? 2ull * (size_t)n_nodes * DIM : 0);
    };
    int C = 64;
    bool use_bf16 = true;
    if (ws_size < need(64, true))  C = 32;
    if (ws_size < need(32, true))  C = 16;
    if (ws_size < need(16, true)) { use_bf16 = false; C = 16; }
    const int chunk = (n_edges + C - 1) / C;

    // ws layout (4B units), all fully overwritten -> NO memset needed:
    // [deg_in npad][offs npad+1][norm_src N][histD C*pairs][histS C*pairs]
    // [rank E][esrc E][xh N*DIM bf16 (optional)]
    int*    deg_in   = (int*)d_ws;
    int*    offs     = deg_in + npad;
    float*  norm_src = (float*)(offs + npad + 1);
    uint*   histD    = (uint*)(norm_src + n_nodes);
    uint*   histS    = histD + (size_t)C * pairs_row;
    int*    rank     = (int*)(histS + (size_t)C * pairs_row);
    int*    esrc     = rank + n_edges;
    ushort* xh       = (ushort*)(esrc + n_edges);

    const int egrid = (n_edges + 255) / 256;

    hist_kernel<<<C, 1024, 0, stream>>>(src, dst, histD, histS, rank,
                                        n_edges, pairs_row, nhalves, chunk);
    prefix_kernel<<<(2 * pairs_row + 255) / 256, 256, 0, stream>>>(
        histD, histS, deg_in, norm_src, pairs_row, n_nodes, C);
    scan4_kernel<<<(npad + 4095) / 4096, 1024, 0, stream>>>(deg_in, offs, npad);
    if (use_bf16) {
        int n4 = n_nodes * DIM / 4;
        cvt_kernel<<<(n4 + 255) / 256, 256, 0, stream>>>(x, xh, n4);
    }
    fill_kernel<<<egrid, 256, 0, stream>>>(src, dst, offs, histD, rank, esrc,
                                           n_edges, pairs_row, chunk);
    if (use_bf16) {
        gather_bf16_kernel<<<(n_nodes + 3) / 4, 256, 0, stream>>>(
            xh, esrc, norm_src, offs, out, n_nodes);
    } else {
        gather_f32_kernel<<<(n_nodes + 3) / 4, 256, 0, stream>>>(
            x, esrc, norm_src, offs, out, n_nodes);
    }
    gemm_kernel<<<(n_nodes + BM - 1) / BM, 256, 0, stream>>>(out, W, b, n_nodes);
}

// Round 8
// 155.181 us; speedup vs baseline: 1.6343x; 1.0570x over previous
//
#include <hip/hip_runtime.h>
#include <hip/hip_bf16.h>

#define DIM 128
#define BM  64
#define HALF_NODES 25088            // nodes per LDS half
#define HALF_PAIRS (HALF_NODES / 2) // 12544 uints
#define FULL_PAIRS (2 * HALF_PAIRS) // 25088 uints = 100 KB LDS window

// ---------------------------------------------------------------------------
// K1: chunked histograms, LDS-only atomics, 2-half window resident (100 KB).
// Block c processes edge chunk c; the dst-pass LDS atomicAdd return value is
// the within-chunk rank -> rank[e].
// ---------------------------------------------------------------------------
__global__ __launch_bounds__(1024) void hist_kernel(const int* __restrict__ src,
                                                    const int* __restrict__ dst,
                                                    uint* __restrict__ histD,
                                                    uint* __restrict__ histS,
                                                    int* __restrict__ rank,
                                                    int n_edges, int pairs_row,
                                                    int nhalves, int chunk) {
    __shared__ uint h[FULL_PAIRS];
    const int c   = blockIdx.x;
    const int tid = threadIdx.x;
    const int beg = c * chunk;
    const int end = min(beg + chunk, n_edges);
    for (int pass = 0; pass < 2; ++pass) {
        const int* key = pass ? src : dst;
        uint* outb     = pass ? histS : histD;
        for (int hbase = 0; hbase < nhalves; hbase += 2) {
            const int plo    = hbase * HALF_PAIRS;
            const int wpairs = min(FULL_PAIRS, pairs_row - plo);
            const int wnodes = wpairs * 2;
            const int lo     = plo * 2;
            for (int j = tid; j < wpairs; j += 1024) h[j] = 0;
            __syncthreads();
            for (int e = beg + tid; e < end; e += 1024) {
                int r = key[e] - lo;
                if ((unsigned)r < (unsigned)wnodes) {
                    uint old = atomicAdd(&h[r >> 1], 1u << ((r & 1) * 16));
                    if (pass == 0)
                        rank[e] = (r & 1) ? (int)(old >> 16) : (int)(old & 0xFFFFu);
                }
            }
            __syncthreads();
            uint* row = outb + (size_t)c * pairs_row + plo;
            for (int j = tid; j < wpairs; j += 1024) row[j] = h[j];
            __syncthreads();
        }
    }
}

// ---------------------------------------------------------------------------
// K2: per-node exclusive prefix over chunks, in place, emitting deg_in and
// norm_src as byproducts.
// ---------------------------------------------------------------------------
__global__ __launch_bounds__(256) void prefix_kernel(uint* __restrict__ histD,
                                                     uint* __restrict__ histS,
                                                     int* __restrict__ deg_in,
                                                     float* __restrict__ norm_src,
                                                     int pairs_row, int n_nodes,
                                                     int nchunk) {
    int id = blockIdx.x * 256 + threadIdx.x;
    bool isS = id >= pairs_row;
    int j = isS ? id - pairs_row : id;
    if (j >= pairs_row) return;
    uint* col = (isS ? histS : histD) + j;
    uint run0 = 0, run1 = 0;
    for (int c = 0; c < nchunk; ++c) {
        uint v = col[(size_t)c * pairs_row];
        col[(size_t)c * pairs_row] = run0 | (run1 << 16);
        run0 += v & 0xFFFFu;
        run1 += v >> 16;
    }
    int n0 = 2 * j, n1 = 2 * j + 1;
    if (isS) {
        if (n0 < n_nodes) norm_src[n0] = rsqrtf(fmaxf((float)run0, 1.0f));
        if (n1 < n_nodes) norm_src[n1] = rsqrtf(fmaxf((float)run1, 1.0f));
    } else {
        deg_in[n0] = (int)run0;
        deg_in[n1] = (int)run1;
    }
}

// ---------------------------------------------------------------------------
// K3: exclusive scan (redundant-prefix, 4 elems/thread, single launch).
// ---------------------------------------------------------------------------
__global__ __launch_bounds__(1024) void scan4_kernel(const int* __restrict__ deg,
                                                     int* __restrict__ offs, int n) {
    __shared__ int w1[16], w2[16];
    const int tid = threadIdx.x, lane = tid & 63, wid = tid >> 6;
    const int base = blockIdx.x * 4096;

    int part = 0;
    for (int i = base ? tid : n; i < base; i += 1024) part += deg[i];
#pragma unroll
    for (int o = 32; o; o >>= 1) part += __shfl_xor(part, o);
    if (lane == 0) w1[wid] = part;
    __syncthreads();
    int prefix = 0;
#pragma unroll
    for (int k = 0; k < 16; ++k) prefix += w1[k];

    int i0 = base + tid * 4;
    int e0 = (i0 + 0 < n) ? deg[i0 + 0] : 0;
    int e1 = (i0 + 1 < n) ? deg[i0 + 1] : 0;
    int e2 = (i0 + 2 < n) ? deg[i0 + 2] : 0;
    int e3 = (i0 + 3 < n) ? deg[i0 + 3] : 0;
    int s  = e0 + e1 + e2 + e3;
    int sc = s;
#pragma unroll
    for (int o = 1; o < 64; o <<= 1) {
        int t = __shfl_up(sc, o);
        if (lane >= o) sc += t;
    }
    if (lane == 63) w2[wid] = sc;
    __syncthreads();
    int wpre = 0;
    for (int k = 0; k < wid; ++k) wpre += w2[k];
    int excl = prefix + wpre + sc - s;
    int o1 = excl + e0, o2 = o1 + e1, o3 = o2 + e2, o4 = o3 + e3;
    if (i0 + 0 < n) offs[i0 + 1] = o1;
    if (i0 + 1 < n) offs[i0 + 2] = o2;
    if (i0 + 2 < n) offs[i0 + 3] = o3;
    if (i0 + 3 < n) offs[i0 + 4] = o4;
    if (base == 0 && tid == 0) offs[0] = 0;
}

// ---------------------------------------------------------------------------
// K4: x -> bf16 copy (round-to-nearest-even).
// ---------------------------------------------------------------------------
__global__ __launch_bounds__(256) void cvt_kernel(const float* __restrict__ x,
                                                  ushort* __restrict__ xh, int n4) {
    int i = blockIdx.x * 256 + threadIdx.x;
    if (i >= n4) return;
    float4 v = reinterpret_cast<const float4*>(x)[i];
    ushort4 h;
    uint u;
    u = __float_as_uint(v.x); h.x = (ushort)((u + 0x7FFFu + ((u >> 16) & 1u)) >> 16);
    u = __float_as_uint(v.y); h.y = (ushort)((u + 0x7FFFu + ((u >> 16) & 1u)) >> 16);
    u = __float_as_uint(v.z); h.z = (ushort)((u + 0x7FFFu + ((u >> 16) & 1u)) >> 16);
    u = __float_as_uint(v.w); h.w = (ushort)((u + 0x7FFFu + ((u >> 16) & 1u)) >> 16);
    reinterpret_cast<ushort4*>(xh)[i] = h;
}

// ---------------------------------------------------------------------------
// K5: streaming scatter, no LDS, no atomics.
// pos = offs[dst] + chunk_prefix[c][dst] + rank[e]   (bijective onto [0,E)).
// ---------------------------------------------------------------------------
__global__ __launch_bounds__(256) void fill_kernel(const int* __restrict__ src,
                                                   const int* __restrict__ dst,
                                                   const int* __restrict__ offs,
                                                   const uint* __restrict__ histD,
                                                   const int* __restrict__ rank,
                                                   int* __restrict__ esrc,
                                                   int n_edges, int pairs_row,
                                                   int chunk) {
    int e = blockIdx.x * 256 + threadIdx.x;
    if (e >= n_edges) return;
    int t = dst[e];
    int c = e / chunk;
    uint pf = histD[(size_t)c * pairs_row + (t >> 1)];
    int pref = (t & 1) ? (int)(pf >> 16) : (int)(pf & 0xFFFFu);
    esrc[offs[t] + pref + rank[e]] = src[e];
}

// ---------------------------------------------------------------------------
// K6a: gather-SpMM, bf16 rows (unchanged).
// ---------------------------------------------------------------------------
__global__ __launch_bounds__(256) void gather_bf16_kernel(const ushort* __restrict__ xh,
                                                          const int* __restrict__ esrc,
                                                          const float* __restrict__ norm_src,
                                                          const int* __restrict__ offs,
                                                          float* __restrict__ out,
                                                          int n_nodes) {
    int node = blockIdx.x * 4 + (threadIdx.x >> 6);
    if (node >= n_nodes) return;
    int lane = threadIdx.x & 63;
    int j = offs[node], end = offs[node + 1];
    int deg = end - j;
    const uint* xp = reinterpret_cast<const uint*>(xh);
    float a0x = 0, a0y = 0, a1x = 0, a1y = 0;
    float a2x = 0, a2y = 0, a3x = 0, a3y = 0;
    for (; j + 3 < end; j += 4) {
        int s0 = esrc[j], s1 = esrc[j + 1], s2 = esrc[j + 2], s3 = esrc[j + 3];
        uint u0 = xp[(size_t)s0 * 64 + lane];
        uint u1 = xp[(size_t)s1 * 64 + lane];
        uint u2 = xp[(size_t)s2 * 64 + lane];
        uint u3 = xp[(size_t)s3 * 64 + lane];
        float n0 = norm_src[s0], n1 = norm_src[s1];
        float n2 = norm_src[s2], n3 = norm_src[s3];
        a0x = fmaf(__uint_as_float(u0 << 16), n0, a0x);
        a0y = fmaf(__uint_as_float(u0 & 0xFFFF0000u), n0, a0y);
        a1x = fmaf(__uint_as_float(u1 << 16), n1, a1x);
        a1y = fmaf(__uint_as_float(u1 & 0xFFFF0000u), n1, a1y);
        a2x = fmaf(__uint_as_float(u2 << 16), n2, a2x);
        a2y = fmaf(__uint_as_float(u2 & 0xFFFF0000u), n2, a2y);
        a3x = fmaf(__uint_as_float(u3 << 16), n3, a3x);
        a3y = fmaf(__uint_as_float(u3 & 0xFFFF0000u), n3, a3y);
    }
    for (; j < end; ++j) {
        int s = esrc[j];
        uint u = xp[(size_t)s * 64 + lane];
        float ns = norm_src[s];
        a0x = fmaf(__uint_as_float(u << 16), ns, a0x);
        a0y = fmaf(__uint_as_float(u & 0xFFFF0000u), ns, a0y);
    }
    float nd = rsqrtf(fmaxf((float)deg, 1.0f));
    float2 r;
    r.x = (a0x + a1x + a2x + a3x) * nd;
    r.y = (a0y + a1y + a2y + a3y) * nd;
    reinterpret_cast<float2*>(out)[(size_t)node * 64 + lane] = r;
}

// ---------------------------------------------------------------------------
// K6b: fp32 fallback gather.
// ---------------------------------------------------------------------------
__global__ __launch_bounds__(256) void gather_f32_kernel(const float* __restrict__ x,
                                                         const int* __restrict__ esrc,
                                                         const float* __restrict__ norm_src,
                                                         const int* __restrict__ offs,
                                                         float* __restrict__ out,
                                                         int n_nodes) {
    int node = blockIdx.x * 4 + (threadIdx.x >> 6);
    if (node >= n_nodes) return;
    int lane = threadIdx.x & 63;
    int j = offs[node], end = offs[node + 1];
    int deg = end - j;
    const float2* xp = reinterpret_cast<const float2*>(x);
    float a0x = 0, a0y = 0, a1x = 0, a1y = 0;
    float a2x = 0, a2y = 0, a3x = 0, a3y = 0;
    for (; j + 3 < end; j += 4) {
        int s0 = esrc[j], s1 = esrc[j + 1], s2 = esrc[j + 2], s3 = esrc[j + 3];
        float2 v0 = xp[(size_t)s0 * 64 + lane];
        float2 v1 = xp[(size_t)s1 * 64 + lane];
        float2 v2 = xp[(size_t)s2 * 64 + lane];
        float2 v3 = xp[(size_t)s3 * 64 + lane];
        float n0 = norm_src[s0], n1 = norm_src[s1];
        float n2 = norm_src[s2], n3 = norm_src[s3];
        a0x = fmaf(v0.x, n0, a0x); a0y = fmaf(v0.y, n0, a0y);
        a1x = fmaf(v1.x, n1, a1x); a1y = fmaf(v1.y, n1, a1y);
        a2x = fmaf(v2.x, n2, a2x); a2y = fmaf(v2.y, n2, a2y);
        a3x = fmaf(v3.x, n3, a3x); a3y = fmaf(v3.y, n3, a3y);
    }
    for (; j < end; ++j) {
        int s = esrc[j];
        float2 v = xp[(size_t)s * 64 + lane];
        float ns = norm_src[s];
        a0x = fmaf(v.x, ns, a0x); a0y = fmaf(v.y, ns, a0y);
    }
    float nd = rsqrtf(fmaxf((float)deg, 1.0f));
    float2 r;
    r.x = (a0x + a1x + a2x + a3x) * nd;
    r.y = (a0y + a1y + a2y + a3y) * nd;
    reinterpret_cast<float2*>(out)[(size_t)node * 64 + lane] = r;
}

// ---------------------------------------------------------------------------
// K7: tiled fp32 GEMM + bias, in-place, OCCUPANCY-FIRST.
//  - Only As [64][132] in LDS (33.8 KB) -> 4 blocks/CU.
//  - W read from GLOBAL in the k-loop: 2 float4/thread/k, 4-fold lane
//    replication + full k-reuse -> L1/L2 resident (W = 64 KB total).
//  - __launch_bounds__(256,4) caps VGPR at 128 so 4 waves/SIMD is real.
// As compute reads: 16 distinct addrs/wave, stride 132 floats -> 8 banks
// x 2-way = conflict-free (2-way is free, m136).
// ---------------------------------------------------------------------------
__global__ __launch_bounds__(256, 4) void gemm_kernel(float* __restrict__ out,
                                                      const float* __restrict__ Wg,
                                                      const float* __restrict__ bg,
                                                      int n_nodes) {
    __shared__ float As[BM][DIM + 4];   // 64 x 132 f32 = 33.8 KB
    const int tid = threadIdx.x;
    const int r0  = blockIdx.x * BM;

    // stage A row-major: global-coalesced b128 read, contiguous b128 LDS write
#pragma unroll
    for (int i = 0; i < 8; ++i) {
        int linear = tid + i * 256;       // 0..2047
        int r  = linear >> 5;             // row within tile
        int k4 = linear & 31;             // float4 index along k
        int row = r0 + r;
        float4 v = (row < n_nodes)
                     ? reinterpret_cast<const float4*>(out)[(size_t)row * 32 + k4]
                     : make_float4(0.f, 0.f, 0.f, 0.f);
        *reinterpret_cast<float4*>(&As[r][k4 * 4]) = v;
    }
    __syncthreads();

    const int cx = tid & 15;   // col groups: cx*4..+3 and 64+cx*4..+3
    const int ry = tid >> 4;   // rows ry*4..+3
    const float4* W4 = reinterpret_cast<const float4*>(Wg);
    float acc[4][8];
#pragma unroll
    for (int rr = 0; rr < 4; ++rr)
#pragma unroll
        for (int cc = 0; cc < 8; ++cc) acc[rr][cc] = 0.f;

#pragma unroll 4
    for (int k = 0; k < DIM; ++k) {
        float4 b0 = W4[k * 32 + cx];         // W[k][cx*4 .. +3]
        float4 b1 = W4[k * 32 + 16 + cx];    // W[k][64+cx*4 .. +3]
        float a0 = As[ry * 4 + 0][k];
        float a1 = As[ry * 4 + 1][k];
        float a2 = As[ry * 4 + 2][k];
        float a3 = As[ry * 4 + 3][k];
        float av[4] = {a0, a1, a2, a3};
        float bv[8] = {b0.x, b0.y, b0.z, b0.w, b1.x, b1.y, b1.z, b1.w};
#pragma unroll
        for (int rr = 0; rr < 4; ++rr)
#pragma unroll
            for (int cc = 0; cc < 8; ++cc)
                acc[rr][cc] = fmaf(av[rr], bv[cc], acc[rr][cc]);
    }

    float bv0[4], bv1[4];
#pragma unroll
    for (int cc = 0; cc < 4; ++cc) {
        bv0[cc] = bg[cx * 4 + cc];
        bv1[cc] = bg[64 + cx * 4 + cc];
    }
#pragma unroll
    for (int rr = 0; rr < 4; ++rr) {
        int row = r0 + ry * 4 + rr;
        if (row >= n_nodes) continue;
        float4 o0, o1;
        o0.x = acc[rr][0] + bv0[0]; o0.y = acc[rr][1] + bv0[1];
        o0.z = acc[rr][2] + bv0[2]; o0.w = acc[rr][3] + bv0[3];
        o1.x = acc[rr][4] + bv1[0]; o1.y = acc[rr][5] + bv1[1];
        o1.z = acc[rr][6] + bv1[2]; o1.w = acc[rr][7] + bv1[3];
        float* op = out + (size_t)row * DIM;
        *reinterpret_cast<float4*>(op + cx * 4)      = o0;
        *reinterpret_cast<float4*>(op + 64 + cx * 4) = o1;
    }
}

extern "C" void kernel_launch(void* const* d_in, const int* in_sizes, int n_in,
                              void* d_out, int out_size, void* d_ws, size_t ws_size,
                              hipStream_t stream) {
    const float* x   = (const float*)d_in[0];
    const int*   src = (const int*)d_in[1];
    const int*   dst = (const int*)d_in[2];
    const float* W   = (const float*)d_in[3];
    const float* b   = (const float*)d_in[4];
    float* out = (float*)d_out;

    const int n_nodes = in_sizes[0] / DIM;
    const int n_edges = in_sizes[1];

    const int nhalves   = (n_nodes + HALF_NODES - 1) / HALF_NODES;
    const int npad      = nhalves * HALF_NODES;
    const int pairs_row = npad / 2;

    auto need = [&](int C, bool bf) -> size_t {
        return 4ull * ((size_t)2 * npad + 1 + n_nodes +
                       2ull * C * pairs_row + 2ull * n_edges) +
               (bf ? 2ull * (size_t)n_nodes * DIM : 0);
    };
    int C = 64;
    bool use_bf16 = true;
    if (ws_size < need(64, true))  C = 32;
    if (ws_size < need(32, true))  C = 16;
    if (ws_size < need(16, true)) { use_bf16 = false; C = 16; }
    const int chunk = (n_edges + C - 1) / C;

    // ws layout (4B units), all fully overwritten -> NO memset needed:
    // [deg_in npad][offs npad+1][norm_src N][histD C*pairs][histS C*pairs]
    // [rank E][esrc E][xh N*DIM bf16 (optional)]
    int*    deg_in   = (int*)d_ws;
    int*    offs     = deg_in + npad;
    float*  norm_src = (float*)(offs + npad + 1);
    uint*   histD    = (uint*)(norm_src + n_nodes);
    uint*   histS    = histD + (size_t)C * pairs_row;
    int*    rank     = (int*)(histS + (size_t)C * pairs_row);
    int*    esrc     = rank + n_edges;
    ushort* xh       = (ushort*)(esrc + n_edges);

    const int egrid = (n_edges + 255) / 256;

    hist_kernel<<<C, 1024, 0, stream>>>(src, dst, histD, histS, rank,
                                        n_edges, pairs_row, nhalves, chunk);
    prefix_kernel<<<(2 * pairs_row + 255) / 256, 256, 0, stream>>>(
        histD, histS, deg_in, norm_src, pairs_row, n_nodes, C);
    scan4_kernel<<<(npad + 4095) / 4096, 1024, 0, stream>>>(deg_in, offs, npad);
    if (use_bf16) {
        int n4 = n_nodes * DIM / 4;
        cvt_kernel<<<(n4 + 255) / 256, 256, 0, stream>>>(x, xh, n4);
    }
    fill_kernel<<<egrid, 256, 0, stream>>>(src, dst, offs, histD, rank, esrc,
                                           n_edges, pairs_row, chunk);
    if (use_bf16) {
        gather_bf16_kernel<<<(n_nodes + 3) / 4, 256, 0, stream>>>(
            xh, esrc, norm_src, offs, out, n_nodes);
    } else {
        gather_f32_kernel<<<(n_nodes + 3) / 4, 256, 0, stream>>>(
            x, esrc, norm_src, offs, out, n_nodes);
    }
    gemm_kernel<<<(n_nodes + BM - 1) / BM, 256, 0, stream>>>(out, W, b, n_nodes);
}

// Round 9
// 141.256 us; speedup vs baseline: 1.7955x; 1.0986x over previous
//
#include <hip/hip_runtime.h>
#include <hip/hip_bf16.h>

#define DIM   128
#define BM    64
#define KSLAB 32
#define HALF_NODES 25088            // nodes per LDS half
#define HALF_PAIRS (HALF_NODES / 2) // 12544 uints
#define FULL_PAIRS (2 * HALF_PAIRS) // 25088 uints = 100 KB LDS window

__device__ __forceinline__ ushort f2bf(float f) {   // round-to-nearest-even
    uint u = __float_as_uint(f);
    return (ushort)((u + 0x7FFFu + ((u >> 16) & 1u)) >> 16);
}

// ---------------------------------------------------------------------------
// K1: chunked histograms, LDS-only atomics (100 KB window covers all nodes).
// dst-pass LDS atomicAdd return value = within-chunk rank -> rank[e].
// ---------------------------------------------------------------------------
__global__ __launch_bounds__(1024) void hist_kernel(const int* __restrict__ src,
                                                    const int* __restrict__ dst,
                                                    uint* __restrict__ histD,
                                                    uint* __restrict__ histS,
                                                    int* __restrict__ rank,
                                                    int n_edges, int pairs_row,
                                                    int nhalves, int chunk) {
    __shared__ uint h[FULL_PAIRS];
    const int c   = blockIdx.x;
    const int tid = threadIdx.x;
    const int beg = c * chunk;
    const int end = min(beg + chunk, n_edges);
    for (int pass = 0; pass < 2; ++pass) {
        const int* key = pass ? src : dst;
        uint* outb     = pass ? histS : histD;
        for (int hbase = 0; hbase < nhalves; hbase += 2) {
            const int plo    = hbase * HALF_PAIRS;
            const int wpairs = min(FULL_PAIRS, pairs_row - plo);
            const int wnodes = wpairs * 2;
            const int lo     = plo * 2;
            for (int j = tid; j < wpairs; j += 1024) h[j] = 0;
            __syncthreads();
            for (int e = beg + tid; e < end; e += 1024) {
                int r = key[e] - lo;
                if ((unsigned)r < (unsigned)wnodes) {
                    uint old = atomicAdd(&h[r >> 1], 1u << ((r & 1) * 16));
                    if (pass == 0)
                        rank[e] = (r & 1) ? (int)(old >> 16) : (int)(old & 0xFFFFu);
                }
            }
            __syncthreads();
            uint* row = outb + (size_t)c * pairs_row + plo;
            for (int j = tid; j < wpairs; j += 1024) row[j] = h[j];
            __syncthreads();
        }
    }
}

// ---------------------------------------------------------------------------
// K2: per-node exclusive prefix over chunks, in place; emits deg_in, norm_src.
// ---------------------------------------------------------------------------
__global__ __launch_bounds__(256) void prefix_kernel(uint* __restrict__ histD,
                                                     uint* __restrict__ histS,
                                                     int* __restrict__ deg_in,
                                                     float* __restrict__ norm_src,
                                                     int pairs_row, int n_nodes,
                                                     int nchunk) {
    int id = blockIdx.x * 256 + threadIdx.x;
    bool isS = id >= pairs_row;
    int j = isS ? id - pairs_row : id;
    if (j >= pairs_row) return;
    uint* col = (isS ? histS : histD) + j;
    uint run0 = 0, run1 = 0;
    for (int c = 0; c < nchunk; ++c) {
        uint v = col[(size_t)c * pairs_row];
        col[(size_t)c * pairs_row] = run0 | (run1 << 16);
        run0 += v & 0xFFFFu;
        run1 += v >> 16;
    }
    int n0 = 2 * j, n1 = 2 * j + 1;
    if (isS) {
        if (n0 < n_nodes) norm_src[n0] = rsqrtf(fmaxf((float)run0, 1.0f));
        if (n1 < n_nodes) norm_src[n1] = rsqrtf(fmaxf((float)run1, 1.0f));
    } else {
        deg_in[n0] = (int)run0;
        deg_in[n1] = (int)run1;
    }
}

// ---------------------------------------------------------------------------
// K3: exclusive scan (redundant-prefix, 4 elems/thread, single launch).
// ---------------------------------------------------------------------------
__global__ __launch_bounds__(1024) void scan4_kernel(const int* __restrict__ deg,
                                                     int* __restrict__ offs, int n) {
    __shared__ int w1[16], w2[16];
    const int tid = threadIdx.x, lane = tid & 63, wid = tid >> 6;
    const int base = blockIdx.x * 4096;

    int part = 0;
    for (int i = base ? tid : n; i < base; i += 1024) part += deg[i];
#pragma unroll
    for (int o = 32; o; o >>= 1) part += __shfl_xor(part, o);
    if (lane == 0) w1[wid] = part;
    __syncthreads();
    int prefix = 0;
#pragma unroll
    for (int k = 0; k < 16; ++k) prefix += w1[k];

    int i0 = base + tid * 4;
    int e0 = (i0 + 0 < n) ? deg[i0 + 0] : 0;
    int e1 = (i0 + 1 < n) ? deg[i0 + 1] : 0;
    int e2 = (i0 + 2 < n) ? deg[i0 + 2] : 0;
    int e3 = (i0 + 3 < n) ? deg[i0 + 3] : 0;
    int s  = e0 + e1 + e2 + e3;
    int sc = s;
#pragma unroll
    for (int o = 1; o < 64; o <<= 1) {
        int t = __shfl_up(sc, o);
        if (lane >= o) sc += t;
    }
    if (lane == 63) w2[wid] = sc;
    __syncthreads();
    int wpre = 0;
    for (int k = 0; k < wid; ++k) wpre += w2[k];
    int excl = prefix + wpre + sc - s;
    int o1 = excl + e0, o2 = o1 + e1, o3 = o2 + e2, o4 = o3 + e3;
    if (i0 + 0 < n) offs[i0 + 1] = o1;
    if (i0 + 1 < n) offs[i0 + 2] = o2;
    if (i0 + 2 < n) offs[i0 + 3] = o3;
    if (i0 + 3 < n) offs[i0 + 4] = o4;
    if (base == 0 && tid == 0) offs[0] = 0;
}

// ---------------------------------------------------------------------------
// K4: streaming scatter, no LDS, no atomics.
// pos = offs[dst] + chunk_prefix[c][dst] + rank[e]   (bijective onto [0,E)).
// ---------------------------------------------------------------------------
__global__ __launch_bounds__(256) void fill_kernel(const int* __restrict__ src,
                                                   const int* __restrict__ dst,
                                                   const int* __restrict__ offs,
                                                   const uint* __restrict__ histD,
                                                   const int* __restrict__ rank,
                                                   int* __restrict__ esrc,
                                                   int n_edges, int pairs_row,
                                                   int chunk) {
    int e = blockIdx.x * 256 + threadIdx.x;
    if (e >= n_edges) return;
    int t = dst[e];
    int c = e / chunk;
    uint pf = histD[(size_t)c * pairs_row + (t >> 1)];
    int pref = (t & 1) ? (int)(pf >> 16) : (int)(pf & 0xFFFFu);
    esrc[offs[t] + pref + rank[e]] = src[e];
}

// ---------------------------------------------------------------------------
// K5: transform-first GEMM.  h[r,:] = bf16( norm_src[r] * (x[r,:] @ W) ).
// As[64][132] (33.8 KB) + W slab [32][128] (16 KB) = 50 KB LDS -> 3 blocks/CU.
// k-loop is pure LDS+FMA (no global): per 4-k group, A read as b128 per row,
// W read as 2x b128 per k; all LDS reads <=2-way bank aliasing (free, m136).
// ---------------------------------------------------------------------------
__global__ __launch_bounds__(256) void gemmx_kernel(const float* __restrict__ x,
                                                    const float* __restrict__ Wg,
                                                    const float* __restrict__ norm_src,
                                                    ushort* __restrict__ h,
                                                    int n_nodes) {
    __shared__ float As[BM][DIM + 4];     // 33.8 KB
    __shared__ float Ws[KSLAB][DIM];      // 16 KB
    const int tid = threadIdx.x;
    const int r0  = blockIdx.x * BM;

    // stage A rows (coalesced b128 in, contiguous b128 to LDS)
#pragma unroll
    for (int i = 0; i < 8; ++i) {
        int linear = tid + i * 256;       // 0..2047
        int r  = linear >> 5;
        int k4 = linear & 31;
        int row = r0 + r;
        float4 v = (row < n_nodes)
                     ? reinterpret_cast<const float4*>(x)[(size_t)row * 32 + k4]
                     : make_float4(0.f, 0.f, 0.f, 0.f);
        *reinterpret_cast<float4*>(&As[r][k4 * 4]) = v;
    }

    const int cx = tid & 15;   // cols cx*4..+3 and 64+cx*4..+3
    const int ry = tid >> 4;   // rows ry*4..+3
    float acc[4][8];
#pragma unroll
    for (int rr = 0; rr < 4; ++rr)
#pragma unroll
        for (int cc = 0; cc < 8; ++cc) acc[rr][cc] = 0.f;

    for (int s = 0; s < DIM / KSLAB; ++s) {
        __syncthreads();   // A-stage done (s=0) / previous slab fully consumed
        // stage W slab s: rows k in [32s, 32s+32) -> 1024 float4 / 256 thr = 4
        const float4* wsrc = reinterpret_cast<const float4*>(Wg + s * KSLAB * DIM);
        float4* wdst = reinterpret_cast<float4*>(&Ws[0][0]);
#pragma unroll
        for (int i = 0; i < 4; ++i) wdst[tid + i * 256] = wsrc[tid + i * 256];
        __syncthreads();

        const int kbase = s * KSLAB;
#pragma unroll
        for (int kk = 0; kk < KSLAB; kk += 4) {
            float4 a0 = *reinterpret_cast<const float4*>(&As[ry * 4 + 0][kbase + kk]);
            float4 a1 = *reinterpret_cast<const float4*>(&As[ry * 4 + 1][kbase + kk]);
            float4 a2 = *reinterpret_cast<const float4*>(&As[ry * 4 + 2][kbase + kk]);
            float4 a3 = *reinterpret_cast<const float4*>(&As[ry * 4 + 3][kbase + kk]);
            float am[4][4];
            am[0][0]=a0.x; am[0][1]=a0.y; am[0][2]=a0.z; am[0][3]=a0.w;
            am[1][0]=a1.x; am[1][1]=a1.y; am[1][2]=a1.z; am[1][3]=a1.w;
            am[2][0]=a2.x; am[2][1]=a2.y; am[2][2]=a2.z; am[2][3]=a2.w;
            am[3][0]=a3.x; am[3][1]=a3.y; am[3][2]=a3.z; am[3][3]=a3.w;
#pragma unroll
            for (int q = 0; q < 4; ++q) {
                float4 b0 = *reinterpret_cast<const float4*>(&Ws[kk + q][cx * 4]);
                float4 b1 = *reinterpret_cast<const float4*>(&Ws[kk + q][64 + cx * 4]);
                float bv[8] = {b0.x, b0.y, b0.z, b0.w, b1.x, b1.y, b1.z, b1.w};
#pragma unroll
                for (int rr = 0; rr < 4; ++rr)
#pragma unroll
                    for (int cc = 0; cc < 8; ++cc)
                        acc[rr][cc] = fmaf(am[rr][q], bv[cc], acc[rr][cc]);
            }
        }
    }

    // epilogue: scale by norm_src[row], convert to bf16, store
#pragma unroll
    for (int rr = 0; rr < 4; ++rr) {
        int row = r0 + ry * 4 + rr;
        if (row >= n_nodes) continue;
        float ns = norm_src[row];
        ushort4 o0, o1;
        o0.x = f2bf(acc[rr][0] * ns); o0.y = f2bf(acc[rr][1] * ns);
        o0.z = f2bf(acc[rr][2] * ns); o0.w = f2bf(acc[rr][3] * ns);
        o1.x = f2bf(acc[rr][4] * ns); o1.y = f2bf(acc[rr][5] * ns);
        o1.z = f2bf(acc[rr][6] * ns); o1.w = f2bf(acc[rr][7] * ns);
        ushort* hp = h + (size_t)row * DIM;
        *reinterpret_cast<ushort4*>(hp + cx * 4)      = o0;
        *reinterpret_cast<ushort4*>(hp + 64 + cx * 4) = o1;
    }
}

// ---------------------------------------------------------------------------
// K6: gather over pre-transformed h.  out[t,:] = nd(t) * sum h[src_e,:] + b.
// One wave per dst node, 1 uint (2 bf16) per lane, x4 unroll; inner loop is
// pure loads+adds (norm already folded into h).
// ---------------------------------------------------------------------------
__global__ __launch_bounds__(256) void gather_kernel(const ushort* __restrict__ h,
                                                     const int* __restrict__ esrc,
                                                     const int* __restrict__ offs,
                                                     const float* __restrict__ bg,
                                                     float* __restrict__ out,
                                                     int n_nodes) {
    int node = blockIdx.x * 4 + (threadIdx.x >> 6);
    if (node >= n_nodes) return;
    int lane = threadIdx.x & 63;
    int j = offs[node], end = offs[node + 1];
    int deg = end - j;
    const uint* hp = reinterpret_cast<const uint*>(h);
    float a0x = 0, a0y = 0, a1x = 0, a1y = 0;
    float a2x = 0, a2y = 0, a3x = 0, a3y = 0;
    for (; j + 3 < end; j += 4) {
        int s0 = esrc[j], s1 = esrc[j + 1], s2 = esrc[j + 2], s3 = esrc[j + 3];
        uint u0 = hp[(size_t)s0 * 64 + lane];
        uint u1 = hp[(size_t)s1 * 64 + lane];
        uint u2 = hp[(size_t)s2 * 64 + lane];
        uint u3 = hp[(size_t)s3 * 64 + lane];
        a0x += __uint_as_float(u0 << 16);
        a0y += __uint_as_float(u0 & 0xFFFF0000u);
        a1x += __uint_as_float(u1 << 16);
        a1y += __uint_as_float(u1 & 0xFFFF0000u);
        a2x += __uint_as_float(u2 << 16);
        a2y += __uint_as_float(u2 & 0xFFFF0000u);
        a3x += __uint_as_float(u3 << 16);
        a3y += __uint_as_float(u3 & 0xFFFF0000u);
    }
    for (; j < end; ++j) {
        int s = esrc[j];
        uint u = hp[(size_t)s * 64 + lane];
        a0x += __uint_as_float(u << 16);
        a0y += __uint_as_float(u & 0xFFFF0000u);
    }
    float nd = rsqrtf(fmaxf((float)deg, 1.0f));
    float2 bv = reinterpret_cast<const float2*>(bg)[lane];
    float2 r;
    r.x = (a0x + a1x + a2x + a3x) * nd + bv.x;
    r.y = (a0y + a1y + a2y + a3y) * nd + bv.y;
    reinterpret_cast<float2*>(out)[(size_t)node * 64 + lane] = r;
}

extern "C" void kernel_launch(void* const* d_in, const int* in_sizes, int n_in,
                              void* d_out, int out_size, void* d_ws, size_t ws_size,
                              hipStream_t stream) {
    const float* x   = (const float*)d_in[0];
    const int*   src = (const int*)d_in[1];
    const int*   dst = (const int*)d_in[2];
    const float* W   = (const float*)d_in[3];
    const float* b   = (const float*)d_in[4];
    float* out = (float*)d_out;

    const int n_nodes = in_sizes[0] / DIM;
    const int n_edges = in_sizes[1];

    const int nhalves   = (n_nodes + HALF_NODES - 1) / HALF_NODES;
    const int npad      = nhalves * HALF_NODES;
    const int pairs_row = npad / 2;

    // chunk-count cascade to fit ws (h bf16 is mandatory: 2*N*DIM bytes)
    auto need = [&](int C) -> size_t {
        return 4ull * ((size_t)2 * npad + 1 + n_nodes +
                       2ull * C * pairs_row + 2ull * n_edges) +
               2ull * (size_t)n_nodes * DIM;
    };
    int C = 64;
    if (ws_size < need(64)) C = 32;
    if (ws_size < need(32)) C = 16;
    const int chunk = (n_edges + C - 1) / C;

    // ws layout (4B units), all fully overwritten -> NO memset needed:
    // [h N*DIM bf16][deg_in npad][offs npad+1][norm_src N]
    // [histD C*pairs][histS C*pairs][rank E][esrc E]
    ushort* h        = (ushort*)d_ws;
    int*    deg_in   = (int*)(h + (size_t)n_nodes * DIM);
    int*    offs     = deg_in + npad;
    float*  norm_src = (float*)(offs + npad + 1);
    uint*   histD    = (uint*)(norm_src + n_nodes);
    uint*   histS    = histD + (size_t)C * pairs_row;
    int*    rank     = (int*)(histS + (size_t)C * pairs_row);
    int*    esrc     = rank + n_edges;

    const int egrid = (n_edges + 255) / 256;

    hist_kernel<<<C, 1024, 0, stream>>>(src, dst, histD, histS, rank,
                                        n_edges, pairs_row, nhalves, chunk);
    prefix_kernel<<<(2 * pairs_row + 255) / 256, 256, 0, stream>>>(
        histD, histS, deg_in, norm_src, pairs_row, n_nodes, C);
    gemmx_kernel<<<(n_nodes + BM - 1) / BM, 256, 0, stream>>>(
        x, W, norm_src, h, n_nodes);
    scan4_kernel<<<(npad + 4095) / 4096, 1024, 0, stream>>>(deg_in, offs, npad);
    fill_kernel<<<egrid, 256, 0, stream>>>(src, dst, offs, histD, rank, esrc,
                                           n_edges, pairs_row, chunk);
    gather_kernel<<<(n_nodes + 3) / 4, 256, 0, stream>>>(
        h, esrc, offs, b, out, n_nodes);
}

// Round 10
// 117.979 us; speedup vs baseline: 2.1497x; 1.1973x over previous
//
#include <hip/hip_runtime.h>
#include <hip/hip_bf16.h>

#define DIM   128
#define BM    64
#define HALF_NODES 25088            // nodes per LDS half
#define HALF_PAIRS (HALF_NODES / 2) // 12544 uints
#define FULL_PAIRS (2 * HALF_PAIRS) // 25088 uints = 100 KB LDS window

typedef short  bf16x8 __attribute__((ext_vector_type(8)));
typedef float  f32x4  __attribute__((ext_vector_type(4)));

__device__ __forceinline__ ushort f2bf(float f) {   // round-to-nearest-even
    uint u = __float_as_uint(f);
    return (ushort)((u + 0x7FFFu + ((u >> 16) & 1u)) >> 16);
}

// ---------------------------------------------------------------------------
// K0: WT[c][k] = bf16(W[k][c])  (once; 16K elems, 64 blocks)
// ---------------------------------------------------------------------------
__global__ __launch_bounds__(256) void cvtw_kernel(const float* __restrict__ W,
                                                   ushort* __restrict__ WT) {
    int idx = blockIdx.x * 256 + threadIdx.x;
    if (idx < DIM * DIM) {
        int k = idx >> 7, c = idx & 127;
        WT[c * DIM + k] = f2bf(W[idx]);
    }
}

// ---------------------------------------------------------------------------
// K1: chunked histograms, LDS-only atomics (100 KB window covers all nodes).
// dst-pass LDS atomicAdd return value = within-chunk rank -> rank[e].
// ---------------------------------------------------------------------------
__global__ __launch_bounds__(1024) void hist_kernel(const int* __restrict__ src,
                                                    const int* __restrict__ dst,
                                                    uint* __restrict__ histD,
                                                    uint* __restrict__ histS,
                                                    int* __restrict__ rank,
                                                    int n_edges, int pairs_row,
                                                    int nhalves, int chunk) {
    __shared__ uint h[FULL_PAIRS];
    const int c   = blockIdx.x;
    const int tid = threadIdx.x;
    const int beg = c * chunk;
    const int end = min(beg + chunk, n_edges);
    for (int pass = 0; pass < 2; ++pass) {
        const int* key = pass ? src : dst;
        uint* outb     = pass ? histS : histD;
        for (int hbase = 0; hbase < nhalves; hbase += 2) {
            const int plo    = hbase * HALF_PAIRS;
            const int wpairs = min(FULL_PAIRS, pairs_row - plo);
            const int wnodes = wpairs * 2;
            const int lo     = plo * 2;
            for (int j = tid; j < wpairs; j += 1024) h[j] = 0;
            __syncthreads();
            for (int e = beg + tid; e < end; e += 1024) {
                int r = key[e] - lo;
                if ((unsigned)r < (unsigned)wnodes) {
                    uint old = atomicAdd(&h[r >> 1], 1u << ((r & 1) * 16));
                    if (pass == 0)
                        rank[e] = (r & 1) ? (int)(old >> 16) : (int)(old & 0xFFFFu);
                }
            }
            __syncthreads();
            uint* row = outb + (size_t)c * pairs_row + plo;
            for (int j = tid; j < wpairs; j += 1024) row[j] = h[j];
            __syncthreads();
        }
    }
}

// ---------------------------------------------------------------------------
// K2: per-node exclusive prefix over chunks, in place; emits deg_in, norm_src.
// ---------------------------------------------------------------------------
__global__ __launch_bounds__(256) void prefix_kernel(uint* __restrict__ histD,
                                                     uint* __restrict__ histS,
                                                     int* __restrict__ deg_in,
                                                     float* __restrict__ norm_src,
                                                     int pairs_row, int n_nodes,
                                                     int nchunk) {
    int id = blockIdx.x * 256 + threadIdx.x;
    bool isS = id >= pairs_row;
    int j = isS ? id - pairs_row : id;
    if (j >= pairs_row) return;
    uint* col = (isS ? histS : histD) + j;
    uint run0 = 0, run1 = 0;
    for (int c = 0; c < nchunk; ++c) {
        uint v = col[(size_t)c * pairs_row];
        col[(size_t)c * pairs_row] = run0 | (run1 << 16);
        run0 += v & 0xFFFFu;
        run1 += v >> 16;
    }
    int n0 = 2 * j, n1 = 2 * j + 1;
    if (isS) {
        if (n0 < n_nodes) norm_src[n0] = rsqrtf(fmaxf((float)run0, 1.0f));
        if (n1 < n_nodes) norm_src[n1] = rsqrtf(fmaxf((float)run1, 1.0f));
    } else {
        deg_in[n0] = (int)run0;
        deg_in[n1] = (int)run1;
    }
}

// ---------------------------------------------------------------------------
// K3: exclusive scan (redundant-prefix, 4 elems/thread, single launch).
// ---------------------------------------------------------------------------
__global__ __launch_bounds__(1024) void scan4_kernel(const int* __restrict__ deg,
                                                     int* __restrict__ offs, int n) {
    __shared__ int w1[16], w2[16];
    const int tid = threadIdx.x, lane = tid & 63, wid = tid >> 6;
    const int base = blockIdx.x * 4096;

    int part = 0;
    for (int i = base ? tid : n; i < base; i += 1024) part += deg[i];
#pragma unroll
    for (int o = 32; o; o >>= 1) part += __shfl_xor(part, o);
    if (lane == 0) w1[wid] = part;
    __syncthreads();
    int prefix = 0;
#pragma unroll
    for (int k = 0; k < 16; ++k) prefix += w1[k];

    int i0 = base + tid * 4;
    int e0 = (i0 + 0 < n) ? deg[i0 + 0] : 0;
    int e1 = (i0 + 1 < n) ? deg[i0 + 1] : 0;
    int e2 = (i0 + 2 < n) ? deg[i0 + 2] : 0;
    int e3 = (i0 + 3 < n) ? deg[i0 + 3] : 0;
    int s  = e0 + e1 + e2 + e3;
    int sc = s;
#pragma unroll
    for (int o = 1; o < 64; o <<= 1) {
        int t = __shfl_up(sc, o);
        if (lane >= o) sc += t;
    }
    if (lane == 63) w2[wid] = sc;
    __syncthreads();
    int wpre = 0;
    for (int k = 0; k < wid; ++k) wpre += w2[k];
    int excl = prefix + wpre + sc - s;
    int o1 = excl + e0, o2 = o1 + e1, o3 = o2 + e2, o4 = o3 + e3;
    if (i0 + 0 < n) offs[i0 + 1] = o1;
    if (i0 + 1 < n) offs[i0 + 2] = o2;
    if (i0 + 2 < n) offs[i0 + 3] = o3;
    if (i0 + 3 < n) offs[i0 + 4] = o4;
    if (base == 0 && tid == 0) offs[0] = 0;
}

// ---------------------------------------------------------------------------
// K4: streaming scatter, no LDS, no atomics.
// ---------------------------------------------------------------------------
__global__ __launch_bounds__(256) void fill_kernel(const int* __restrict__ src,
                                                   const int* __restrict__ dst,
                                                   const int* __restrict__ offs,
                                                   const uint* __restrict__ histD,
                                                   const int* __restrict__ rank,
                                                   int* __restrict__ esrc,
                                                   int n_edges, int pairs_row,
                                                   int chunk) {
    int e = blockIdx.x * 256 + threadIdx.x;
    if (e >= n_edges) return;
    int t = dst[e];
    int c = e / chunk;
    uint pf = histD[(size_t)c * pairs_row + (t >> 1)];
    int pref = (t & 1) ? (int)(pf >> 16) : (int)(pf & 0xFFFFu);
    esrc[offs[t] + pref + rank[e]] = src[e];
}

// ---------------------------------------------------------------------------
// K5: MFMA transform GEMM.  h[r,:] = bf16( norm_src[r] * (x[r,:] @ W) ).
// 4 waves/block, wave w owns rows r0+16w..+15, all 128 cols (8 ctiles).
// mfma_f32_16x16x32_bf16: A lane l holds A[l&15][(l>>4)*8+j];
//                          B lane l holds B[(l>>4)*8+j][l&15];
//                          C/D: col=lane&15, row=(lane>>4)*4+reg  [m89].
// A-frags: direct from global x (fp32->bf16 in regs); wave's loads per kstep
// cover 16 full 128B lines (coalesced).  B: WsT[c][k] bf16 in LDS (32 KB),
// XOR-swizzled (byte ^= (c&7)<<4) -> conflict-free b128 reads (G4/T2).
// ---------------------------------------------------------------------------
__global__ __launch_bounds__(256, 4) void gemmx_kernel(const float* __restrict__ x,
                                                       const ushort* __restrict__ WT,
                                                       const float* __restrict__ norm_src,
                                                       ushort* __restrict__ h,
                                                       int n_nodes) {
    __shared__ ushort WsT[DIM * DIM];   // 32 KB, swizzled [c][k]
    const int tid = threadIdx.x;

    // stage WsT: coalesced uint4 in, swizzled uint4 to LDS
    {
        const uint4* wsrc = reinterpret_cast<const uint4*>(WT);
#pragma unroll
        for (int i = 0; i < 8; ++i) {
            int linear = tid + i * 256;           // 0..2047 16B-units
            uint4 v = wsrc[linear];
            int byte = linear * 16;
            int c = byte >> 8;
            int swz = byte ^ ((c & 7) << 4);
            *reinterpret_cast<uint4*>(reinterpret_cast<char*>(WsT) + swz) = v;
        }
    }
    __syncthreads();

    const int lane = tid & 63;
    const int w    = tid >> 6;
    const int r0   = blockIdx.x * BM;
    const int rowm = r0 + w * 16 + (lane & 15);
    const int rowc = min(rowm, n_nodes - 1);      // clamp; garbage rows unused
    const float4* X4 = reinterpret_cast<const float4*>(x);

    f32x4 acc[8];
#pragma unroll
    for (int t = 0; t < 8; ++t) acc[t] = (f32x4){0.f, 0.f, 0.f, 0.f};

#pragma unroll
    for (int s = 0; s < 4; ++s) {
        // A fragment: x[rowc][s*32 + (lane>>4)*8 .. +7] -> bf16x8
        int idx = rowc * 32 + s * 8 + (lane >> 4) * 2;
        float4 v0 = X4[idx];
        float4 v1 = X4[idx + 1];
        bf16x8 a;
        a[0] = (short)f2bf(v0.x); a[1] = (short)f2bf(v0.y);
        a[2] = (short)f2bf(v0.z); a[3] = (short)f2bf(v0.w);
        a[4] = (short)f2bf(v1.x); a[5] = (short)f2bf(v1.y);
        a[6] = (short)f2bf(v1.z); a[7] = (short)f2bf(v1.w);
#pragma unroll
        for (int t = 0; t < 8; ++t) {
            int c   = t * 16 + (lane & 15);
            int ofs = c * 256 + s * 64 + (lane >> 4) * 16;
            ofs ^= (c & 7) << 4;
            bf16x8 b = *reinterpret_cast<const bf16x8*>(
                reinterpret_cast<const char*>(WsT) + ofs);
            acc[t] = __builtin_amdgcn_mfma_f32_16x16x32_bf16(a, b, acc[t], 0, 0, 0);
        }
    }

    // epilogue: scale by norm_src[row], bf16, store
#pragma unroll
    for (int i = 0; i < 4; ++i) {
        int row = r0 + w * 16 + (lane >> 4) * 4 + i;
        if (row < n_nodes) {
            float ns = norm_src[row];
            ushort* hp = h + (size_t)row * DIM + (lane & 15);
#pragma unroll
            for (int t = 0; t < 8; ++t)
                hp[t * 16] = f2bf(acc[t][i] * ns);
        }
    }
}

// ---------------------------------------------------------------------------
// K6: gather over pre-transformed h, x8 unroll (8 independent loads in
// flight against L3 latency).  out[t,:] = nd(t) * sum h[src_e,:] + b.
// ---------------------------------------------------------------------------
__global__ __launch_bounds__(256) void gather_kernel(const ushort* __restrict__ h,
                                                     const int* __restrict__ esrc,
                                                     const int* __restrict__ offs,
                                                     const float* __restrict__ bg,
                                                     float* __restrict__ out,
                                                     int n_nodes) {
    int node = blockIdx.x * 4 + (threadIdx.x >> 6);
    if (node >= n_nodes) return;
    int lane = threadIdx.x & 63;
    int j = offs[node], end = offs[node + 1];
    int deg = end - j;
    const uint* hp = reinterpret_cast<const uint*>(h);
    float ax[8], ay[8];
#pragma unroll
    for (int q = 0; q < 8; ++q) { ax[q] = 0.f; ay[q] = 0.f; }
    for (; j + 7 < end; j += 8) {
        int   si[8];
        uint  u[8];
#pragma unroll
        for (int q = 0; q < 8; ++q) si[q] = esrc[j + q];
#pragma unroll
        for (int q = 0; q < 8; ++q) u[q] = hp[(size_t)si[q] * 64 + lane];
#pragma unroll
        for (int q = 0; q < 8; ++q) {
            ax[q] += __uint_as_float(u[q] << 16);
            ay[q] += __uint_as_float(u[q] & 0xFFFF0000u);
        }
    }
    for (; j + 3 < end; j += 4) {
        int  si[4];
        uint u[4];
#pragma unroll
        for (int q = 0; q < 4; ++q) si[q] = esrc[j + q];
#pragma unroll
        for (int q = 0; q < 4; ++q) u[q] = hp[(size_t)si[q] * 64 + lane];
#pragma unroll
        for (int q = 0; q < 4; ++q) {
            ax[q] += __uint_as_float(u[q] << 16);
            ay[q] += __uint_as_float(u[q] & 0xFFFF0000u);
        }
    }
    for (; j < end; ++j) {
        uint u = hp[(size_t)esrc[j] * 64 + lane];
        ax[0] += __uint_as_float(u << 16);
        ay[0] += __uint_as_float(u & 0xFFFF0000u);
    }
    float sx = ((ax[0] + ax[1]) + (ax[2] + ax[3])) + ((ax[4] + ax[5]) + (ax[6] + ax[7]));
    float sy = ((ay[0] + ay[1]) + (ay[2] + ay[3])) + ((ay[4] + ay[5]) + (ay[6] + ay[7]));
    float nd = rsqrtf(fmaxf((float)deg, 1.0f));
    float2 bv = reinterpret_cast<const float2*>(bg)[lane];
    float2 r;
    r.x = sx * nd + bv.x;
    r.y = sy * nd + bv.y;
    reinterpret_cast<float2*>(out)[(size_t)node * 64 + lane] = r;
}

extern "C" void kernel_launch(void* const* d_in, const int* in_sizes, int n_in,
                              void* d_out, int out_size, void* d_ws, size_t ws_size,
                              hipStream_t stream) {
    const float* x   = (const float*)d_in[0];
    const int*   src = (const int*)d_in[1];
    const int*   dst = (const int*)d_in[2];
    const float* W   = (const float*)d_in[3];
    const float* b   = (const float*)d_in[4];
    float* out = (float*)d_out;

    const int n_nodes = in_sizes[0] / DIM;
    const int n_edges = in_sizes[1];

    const int nhalves   = (n_nodes + HALF_NODES - 1) / HALF_NODES;
    const int npad      = nhalves * HALF_NODES;
    const int pairs_row = npad / 2;

    auto need = [&](int C) -> size_t {
        return 2ull * n_nodes * DIM + 2ull * DIM * DIM +
               4ull * ((size_t)2 * npad + 1 + n_nodes +
                       2ull * C * pairs_row + 2ull * n_edges);
    };
    int C = 64;
    if (ws_size < need(64)) C = 32;
    if (ws_size < need(32)) C = 16;
    const int chunk = (n_edges + C - 1) / C;

    // ws layout (all fully overwritten -> NO memset needed):
    // [h N*DIM bf16][WT 128*128 bf16][deg_in npad][offs npad+1][norm_src N]
    // [histD C*pairs][histS C*pairs][rank E][esrc E]
    ushort* h        = (ushort*)d_ws;
    ushort* WT       = h + (size_t)n_nodes * DIM;
    int*    deg_in   = (int*)(WT + DIM * DIM);
    int*    offs     = deg_in + npad;
    float*  norm_src = (float*)(offs + npad + 1);
    uint*   histD    = (uint*)(norm_src + n_nodes);
    uint*   histS    = histD + (size_t)C * pairs_row;
    int*    rank     = (int*)(histS + (size_t)C * pairs_row);
    int*    esrc     = rank + n_edges;

    const int egrid = (n_edges + 255) / 256;

    cvtw_kernel<<<(DIM * DIM + 255) / 256, 256, 0, stream>>>(W, WT);
    hist_kernel<<<C, 1024, 0, stream>>>(src, dst, histD, histS, rank,
                                        n_edges, pairs_row, nhalves, chunk);
    prefix_kernel<<<(2 * pairs_row + 255) / 256, 256, 0, stream>>>(
        histD, histS, deg_in, norm_src, pairs_row, n_nodes, C);
    gemmx_kernel<<<(n_nodes + BM - 1) / BM, 256, 0, stream>>>(
        x, WT, norm_src, h, n_nodes);
    scan4_kernel<<<(npad + 4095) / 4096, 1024, 0, stream>>>(deg_in, offs, npad);
    fill_kernel<<<egrid, 256, 0, stream>>>(src, dst, offs, histD, rank, esrc,
                                           n_edges, pairs_row, chunk);
    gather_kernel<<<(n_nodes + 3) / 4, 256, 0, stream>>>(
        h, esrc, offs, b, out, n_nodes);
}